// Round 1
// baseline (2676.536 us; speedup 1.0000x reference)
//
#include <hip/hip_runtime.h>
#include <hip/hip_bf16.h>
#include <math.h>

typedef __bf16 bf16;
typedef __attribute__((ext_vector_type(8))) __bf16 v8bf;
typedef __attribute__((ext_vector_type(4))) float v4f;

// ---------------------------------------------------------------------------
// small prep kernels
// ---------------------------------------------------------------------------
__global__ void wconv_t(const float* __restrict__ W, bf16* __restrict__ Wt, int Kd, int Nd) {
  int e = blockIdx.x * 256 + threadIdx.x;
  if (e < Kd * Nd) {
    int k = e / Nd, n = e - k * Nd;
    Wt[n * Kd + k] = (bf16)W[e];   // store transposed [N][K] for gemm_bt
  }
}

__global__ void cbt_k(const float* __restrict__ cb, float* __restrict__ cbT) {
  int e = blockIdx.x * 256 + threadIdx.x;   // 3*256*64 total
  if (e < 3 * 256 * 64) {
    int l = e >> 14, rem = e & 16383;
    int c = rem >> 6, d = rem & 63;
    cbT[l * 16384 + d * 256 + c] = cb[e];   // [l][d][c]
  }
}

__global__ void nhn_k(const float* __restrict__ cb, float* __restrict__ nhn) {
  int l = blockIdx.x, c = threadIdx.x;      // grid 3 x 256
  const float* p = cb + l * 16384 + c * 64;
  double s = 0.0;
  for (int d = 0; d < 64; ++d) { double v = (double)p[d]; s += v * v; }
  nhn[l * 256 + c] = (float)(-0.5 * s);
}

// ---------------------------------------------------------------------------
// fp32 GEMM, 128x128 tile, BK=32, 8x8 per thread.
// EPI: 0 = SiLU->f32, 1 = +bias->f32, 2 = +bias, LN(128), ReLU -> f32 (needs gridDim.x==1,N==128)
// ---------------------------------------------------------------------------
template <int EPI>
__global__ __launch_bounds__(256, 2) void sgemm128(
    const float* __restrict__ A, const float* __restrict__ W,
    const float* __restrict__ bias, const float* __restrict__ lng,
    const float* __restrict__ lnb, float* __restrict__ C, int N, int Kd) {
  __shared__ float As[32][132];   // [k][m], padded
  __shared__ float Bs[32][128];   // [k][n]
  const int tid = threadIdx.x;
  const int w = tid >> 6, l = tid & 63;
  int tx, ty;
  if (EPI == 2) { tx = tid & 15; ty = tid >> 4; }          // row in one 16-lane group
  else { tx = ((w & 1) << 3) | (l & 7); ty = ((w >> 1) << 3) | (l >> 3); }
  const int bm = blockIdx.y << 7, bn = blockIdx.x << 7;

  float acc[8][8];
#pragma unroll
  for (int i = 0; i < 8; ++i)
#pragma unroll
    for (int j = 0; j < 8; ++j) acc[i][j] = 0.0f;

  for (int k0 = 0; k0 < Kd; k0 += 32) {
    __syncthreads();
#pragma unroll
    for (int jj = 0; jj < 4; ++jj) {
      int p = tid + 256 * jj;
      int arow = p >> 3, aks = (p & 7) << 2;
      float4 v = *(const float4*)(A + (size_t)(bm + arow) * Kd + k0 + aks);
      As[aks][arow] = v.x; As[aks + 1][arow] = v.y;
      As[aks + 2][arow] = v.z; As[aks + 3][arow] = v.w;
      int bk = p >> 5, bns = (p & 31) << 2;
      float4 u = *(const float4*)(W + (size_t)(k0 + bk) * N + bn + bns);
      *(float4*)(&Bs[bk][bns]) = u;
    }
    __syncthreads();
    float cacc[8][8];   // per-BK chunk accumulator (precision: shortens fp32 random walk)
#pragma unroll
    for (int i = 0; i < 8; ++i)
#pragma unroll
      for (int j = 0; j < 8; ++j) cacc[i][j] = 0.0f;
#pragma unroll 4
    for (int kk = 0; kk < 32; ++kk) {
      float a[8], b[8];
#pragma unroll
      for (int i = 0; i < 8; ++i) a[i] = As[kk][ty * 8 + i];
#pragma unroll
      for (int j = 0; j < 8; ++j) b[j] = Bs[kk][tx * 8 + j];
#pragma unroll
      for (int i = 0; i < 8; ++i)
#pragma unroll
        for (int j = 0; j < 8; ++j) cacc[i][j] = fmaf(a[i], b[j], cacc[i][j]);
    }
#pragma unroll
    for (int i = 0; i < 8; ++i)
#pragma unroll
      for (int j = 0; j < 8; ++j) acc[i][j] += cacc[i][j];
  }

  const int colb = bn + tx * 8;
  if (EPI == 0) {
#pragma unroll
    for (int i = 0; i < 8; ++i) {
      int row = bm + ty * 8 + i;
      float o[8];
#pragma unroll
      for (int j = 0; j < 8; ++j) { float v = acc[i][j]; o[j] = v / (1.0f + expf(-v)); }
      *(float4*)(C + (size_t)row * N + colb) = make_float4(o[0], o[1], o[2], o[3]);
      *(float4*)(C + (size_t)row * N + colb + 4) = make_float4(o[4], o[5], o[6], o[7]);
    }
  } else if (EPI == 1) {
    float bb[8];
#pragma unroll
    for (int j = 0; j < 8; ++j) bb[j] = bias[colb + j];
#pragma unroll
    for (int i = 0; i < 8; ++i) {
      int row = bm + ty * 8 + i;
      float o[8];
#pragma unroll
      for (int j = 0; j < 8; ++j) o[j] = acc[i][j] + bb[j];
      *(float4*)(C + (size_t)row * N + colb) = make_float4(o[0], o[1], o[2], o[3]);
      *(float4*)(C + (size_t)row * N + colb + 4) = make_float4(o[4], o[5], o[6], o[7]);
    }
  } else {
    float bb[8], lg[8], lb[8];
#pragma unroll
    for (int j = 0; j < 8; ++j) { bb[j] = bias[colb + j]; lg[j] = lng[colb + j]; lb[j] = lnb[colb + j]; }
#pragma unroll
    for (int i = 0; i < 8; ++i) {
      int row = bm + ty * 8 + i;
      float v[8]; float s = 0.0f;
#pragma unroll
      for (int j = 0; j < 8; ++j) { v[j] = acc[i][j] + bb[j]; s += v[j]; }
      s += __shfl_xor(s, 1); s += __shfl_xor(s, 2); s += __shfl_xor(s, 4); s += __shfl_xor(s, 8);
      float mean = s * (1.0f / 128.0f);
      float ss = 0.0f;
#pragma unroll
      for (int j = 0; j < 8; ++j) { float t = v[j] - mean; ss += t * t; }
      ss += __shfl_xor(ss, 1); ss += __shfl_xor(ss, 2); ss += __shfl_xor(ss, 4); ss += __shfl_xor(ss, 8);
      float rs = 1.0f / sqrtf(ss * (1.0f / 128.0f) + 1e-5f);
      float o[8];
#pragma unroll
      for (int j = 0; j < 8; ++j) o[j] = fmaxf((v[j] - mean) * rs * lg[j] + lb[j], 0.0f);
      *(float4*)(C + (size_t)row * N + colb) = make_float4(o[0], o[1], o[2], o[3]);
      *(float4*)(C + (size_t)row * N + colb + 4) = make_float4(o[4], o[5], o[6], o[7]);
    }
  }
}

// ---------------------------------------------------------------------------
// fp32 GEMM, 128x64 tile (N fixed 64), BK=32, 8x4 per thread.
// EPI: 0 = l2norm row -> C, 1 = +bias -> C, 2 = gate (sigmoid->C, gate*aux->C2)
// ---------------------------------------------------------------------------
template <int EPI>
__global__ __launch_bounds__(256, 2) void sgemm64(
    const float* __restrict__ A, const float* __restrict__ W,
    const float* __restrict__ bias, const float* __restrict__ aux,
    float* __restrict__ C, float* __restrict__ C2, int Kd) {
  __shared__ float As[32][132];
  __shared__ float Bs[32][64];
  const int tid = threadIdx.x;
  const int tx = tid & 15, ty = tid >> 4;
  const int bm = blockIdx.x << 7;

  float acc[8][4];
#pragma unroll
  for (int i = 0; i < 8; ++i)
#pragma unroll
    for (int j = 0; j < 4; ++j) acc[i][j] = 0.0f;

  for (int k0 = 0; k0 < Kd; k0 += 32) {
    __syncthreads();
#pragma unroll
    for (int jj = 0; jj < 4; ++jj) {
      int p = tid + 256 * jj;
      int arow = p >> 3, aks = (p & 7) << 2;
      float4 v = *(const float4*)(A + (size_t)(bm + arow) * Kd + k0 + aks);
      As[aks][arow] = v.x; As[aks + 1][arow] = v.y;
      As[aks + 2][arow] = v.z; As[aks + 3][arow] = v.w;
    }
#pragma unroll
    for (int jj = 0; jj < 2; ++jj) {
      int p = tid + 256 * jj;
      int bk = p >> 4, bns = (p & 15) << 2;
      float4 u = *(const float4*)(W + (size_t)(k0 + bk) * 64 + bns);
      *(float4*)(&Bs[bk][bns]) = u;
    }
    __syncthreads();
    float cacc[8][4];
#pragma unroll
    for (int i = 0; i < 8; ++i)
#pragma unroll
      for (int j = 0; j < 4; ++j) cacc[i][j] = 0.0f;
#pragma unroll 4
    for (int kk = 0; kk < 32; ++kk) {
      float a[8], b[4];
#pragma unroll
      for (int i = 0; i < 8; ++i) a[i] = As[kk][ty * 8 + i];
#pragma unroll
      for (int j = 0; j < 4; ++j) b[j] = Bs[kk][tx * 4 + j];
#pragma unroll
      for (int i = 0; i < 8; ++i)
#pragma unroll
        for (int j = 0; j < 4; ++j) cacc[i][j] = fmaf(a[i], b[j], cacc[i][j]);
    }
#pragma unroll
    for (int i = 0; i < 8; ++i)
#pragma unroll
      for (int j = 0; j < 4; ++j) acc[i][j] += cacc[i][j];
  }

  const int colb = tx * 4;
  if (EPI == 0) {           // l2norm(z) -> rn
#pragma unroll
    for (int i = 0; i < 8; ++i) {
      int row = bm + ty * 8 + i;
      float ss = 0.0f;
#pragma unroll
      for (int j = 0; j < 4; ++j) ss += acc[i][j] * acc[i][j];
      ss += __shfl_xor(ss, 1); ss += __shfl_xor(ss, 2); ss += __shfl_xor(ss, 4); ss += __shfl_xor(ss, 8);
      float nrm = fmaxf(sqrtf(ss), 1e-12f);
      *(float4*)(C + (size_t)row * 64 + colb) =
          make_float4(acc[i][0] / nrm, acc[i][1] / nrm, acc[i][2] / nrm, acc[i][3] / nrm);
    }
  } else if (EPI == 1) {
    float bb[4];
#pragma unroll
    for (int j = 0; j < 4; ++j) bb[j] = bias[colb + j];
#pragma unroll
    for (int i = 0; i < 8; ++i) {
      int row = bm + ty * 8 + i;
      *(float4*)(C + (size_t)row * 64 + colb) =
          make_float4(acc[i][0] + bb[0], acc[i][1] + bb[1], acc[i][2] + bb[2], acc[i][3] + bb[3]);
    }
  } else {                  // gate: sigmoid -> C (gate_values), gate*collab -> C2 (denoised)
    float bb[4];
#pragma unroll
    for (int j = 0; j < 4; ++j) bb[j] = bias[colb + j];
#pragma unroll
    for (int i = 0; i < 8; ++i) {
      int row = bm + ty * 8 + i;
      float4 av = *(const float4*)(aux + (size_t)row * 64 + colb);
      float g[4];
#pragma unroll
      for (int j = 0; j < 4; ++j) g[j] = 1.0f / (1.0f + expf(-(acc[i][j] + bb[j])));
      *(float4*)(C + (size_t)row * 64 + colb) = make_float4(g[0], g[1], g[2], g[3]);
      *(float4*)(C2 + (size_t)row * 64 + colb) =
          make_float4(g[0] * av.x, g[1] * av.y, g[2] * av.z, g[3] * av.w);
    }
  }
}

// ---------------------------------------------------------------------------
// fusion layernorm over 832 = concat(sem 768, denoised 64); wave per row
// ---------------------------------------------------------------------------
__global__ __launch_bounds__(256) void fuse_ln(
    const float* __restrict__ sem, const float* __restrict__ den,
    const float* __restrict__ fg, const float* __restrict__ fb,
    float* __restrict__ fused) {
  const int w = threadIdx.x >> 6, l = threadIdx.x & 63;
  float fgv[13], fbv[13];
#pragma unroll
  for (int q = 0; q < 12; ++q) { fgv[q] = fg[q * 64 + l]; fbv[q] = fb[q * 64 + l]; }
  fgv[12] = fg[768 + l]; fbv[12] = fb[768 + l];
  for (int it = 0; it < 4; ++it) {
    int r = (blockIdx.x * 4 + w) * 4 + it;
    float sv[12];
#pragma unroll
    for (int q = 0; q < 12; ++q) sv[q] = sem[(size_t)r * 768 + q * 64 + l];
    float dv = den[(size_t)r * 64 + l];
    float s = dv;
#pragma unroll
    for (int q = 0; q < 12; ++q) s += sv[q];
#pragma unroll
    for (int m = 1; m < 64; m <<= 1) s += __shfl_xor(s, m, 64);
    float mean = s * (1.0f / 832.0f);
    float t0 = dv - mean;
    float ss = t0 * t0;
#pragma unroll
    for (int q = 0; q < 12; ++q) { float t = sv[q] - mean; ss += t * t; }
#pragma unroll
    for (int m = 1; m < 64; m <<= 1) ss += __shfl_xor(ss, m, 64);
    float sc = 1.0f / sqrtf(ss * (1.0f / 832.0f) + 1e-5f);
#pragma unroll
    for (int q = 0; q < 12; ++q)
      fused[(size_t)r * 832 + q * 64 + l] = (sv[q] - mean) * sc * fgv[q] + fbv[q];
    fused[(size_t)r * 832 + 768 + l] = t0 * sc * fgv[12] + fbv[12];
  }
}

// ---------------------------------------------------------------------------
// RQ argmax + update; wave per row, 16 rows/wave
// ---------------------------------------------------------------------------
template <int LAYER>
__global__ __launch_bounds__(256) void argupd(
    const float* __restrict__ scores, const float* __restrict__ cbl,
    float* __restrict__ rn, float* __restrict__ zq, float* __restrict__ codes,
    float* __restrict__ loss, bf16* __restrict__ zqb) {
  const int w = threadIdx.x >> 6, l = threadIdx.x & 63;
  const int base = (blockIdx.x * 4 + w) * 16;
  float lacc = 0.0f;
  for (int it = 0; it < 16; ++it) {
    int r = base + it;
    float4 s4 = *(const float4*)(scores + (size_t)r * 256 + l * 4);
    float bs = s4.x; int bi = l * 4;
    if (s4.y > bs) { bs = s4.y; bi = l * 4 + 1; }
    if (s4.z > bs) { bs = s4.z; bi = l * 4 + 2; }
    if (s4.w > bs) { bs = s4.w; bi = l * 4 + 3; }
#pragma unroll
    for (int m = 1; m < 64; m <<= 1) {
      float os = __shfl_xor(bs, m, 64);
      int oi = __shfl_xor(bi, m, 64);
      if (os > bs || (os == bs && oi < bi)) { bs = os; bi = oi; }
    }
    float e = cbl[bi * 64 + l];
    float rl = rn[(size_t)r * 64 + l];
    float emr = e - rl;
    float zql = rl + emr;          // straight-through forward value, ref rounding order
    lacc += emr * emr;
    if (l == 0) codes[r * 3 + LAYER] = (float)bi;
    if (LAYER == 0) {
      zq[(size_t)r * 64 + l] = zql;
    } else if (LAYER == 1) {
      zq[(size_t)r * 64 + l] += zql;
    } else {
      float tot = zq[(size_t)r * 64 + l] + zql;
      zq[(size_t)r * 64 + l] = tot;
      zqb[(size_t)r * 64 + l] = (bf16)tot;
    }
    if (LAYER < 2) {
      float rnew = rl - zql;
      float ss = rnew * rnew;
#pragma unroll
      for (int m = 1; m < 64; m <<= 1) ss += __shfl_xor(ss, m, 64);
      float nrm = fmaxf(sqrtf(ss), 1e-12f);
      rn[(size_t)r * 64 + l] = rnew / nrm;
    }
  }
#pragma unroll
  for (int m = 1; m < 64; m <<= 1) lacc += __shfl_xor(lacc, m, 64);
  if (l == 0) {
    float v = lacc * (1.0f / 4194304.0f);   // 1/(65536*64), exact pow2
    atomicAdd(loss, v);
    atomicAdd(loss + 1, v);
  }
}

// ---------------------------------------------------------------------------
// bf16 MFMA GEMM (gemm_bt, m97 structure): 128x128 tile, BK=32, global_load_lds
// EPI: 0 = SiLU->bf16, 1 = +bias->bf16, 2 = +bias->f32
// ---------------------------------------------------------------------------
typedef __attribute__((address_space(3))) void lds_void_t;
typedef __attribute__((address_space(1))) const void gbl_void_t;
__device__ __forceinline__ void gl_lds16(const void* g, void* l) {
  __builtin_amdgcn_global_load_lds((gbl_void_t*)g, (lds_void_t*)l, 16, 0, 0);
}

template <int EPI>
__global__ __launch_bounds__(256, 3) void bgemm(
    const bf16* __restrict__ A, const bf16* __restrict__ Wt,
    const float* __restrict__ bias, void* __restrict__ Cv, int N, int Kd) {
  __shared__ __align__(16) bf16 As[128 * 32];
  __shared__ __align__(16) bf16 Bs[128 * 32];
  const int tid = threadIdx.x;
  const int w = tid >> 6, l = tid & 63;
  const int bm = blockIdx.y << 7, bn = blockIdx.x << 7;
  const int wm = (w >> 1) << 6, wn = (w & 1) << 6;

  v4f acc[4][4];
  v4f z4 = {0.0f, 0.0f, 0.0f, 0.0f};
#pragma unroll
  for (int i = 0; i < 4; ++i)
#pragma unroll
    for (int j = 0; j < 4; ++j) acc[i][j] = z4;

  const int srow = (w << 5) + (l >> 2);
  const int skc = (l & 3) << 3;
  const bf16* ga0 = A + (size_t)(bm + srow) * Kd + skc;
  const bf16* gb0 = Wt + (size_t)(bn + srow) * Kd + skc;
  char* la0 = (char*)As + (w << 11);
  char* lb0 = (char*)Bs + (w << 11);

  for (int k0 = 0; k0 < Kd; k0 += 32) {
    __syncthreads();
    gl_lds16(ga0 + k0, la0);
    gl_lds16(ga0 + (size_t)16 * Kd + k0, la0 + 1024);
    gl_lds16(gb0 + k0, lb0);
    gl_lds16(gb0 + (size_t)16 * Kd + k0, lb0 + 1024);
    __syncthreads();
    v8bf af[4], bfr[4];
#pragma unroll
    for (int f = 0; f < 4; ++f) {
      af[f] = *(const v8bf*)(As + (wm + f * 16 + (l & 15)) * 32 + ((l >> 4) << 3));
      bfr[f] = *(const v8bf*)(Bs + (wn + f * 16 + (l & 15)) * 32 + ((l >> 4) << 3));
    }
#pragma unroll
    for (int mf = 0; mf < 4; ++mf)
#pragma unroll
      for (int nf = 0; nf < 4; ++nf)
        acc[mf][nf] = __builtin_amdgcn_mfma_f32_16x16x32_bf16(af[mf], bfr[nf], acc[mf][nf], 0, 0, 0);
  }

  const int cbase = bn + wn + (l & 15);
  float bb[4];
  if (EPI != 0) {
#pragma unroll
    for (int nf = 0; nf < 4; ++nf) bb[nf] = bias[cbase + nf * 16];
  }
#pragma unroll
  for (int mf = 0; mf < 4; ++mf) {
#pragma unroll
    for (int i = 0; i < 4; ++i) {
      int row = bm + wm + mf * 16 + ((l >> 4) << 2) + i;
#pragma unroll
      for (int nf = 0; nf < 4; ++nf) {
        int col = cbase + nf * 16;
        float v = acc[mf][nf][i];
        if (EPI == 0) {
          v = v / (1.0f + __expf(-v));
          ((bf16*)Cv)[(size_t)row * N + col] = (bf16)v;
        } else if (EPI == 1) {
          v += bb[nf];
          ((bf16*)Cv)[(size_t)row * N + col] = (bf16)v;
        } else {
          v += bb[nf];
          ((float*)Cv)[(size_t)row * N + col] = v;
        }
      }
    }
  }
}

// ---------------------------------------------------------------------------
// row layernorm + relu, in place; block per row
// ---------------------------------------------------------------------------
template <int VPT, typename T>
__global__ __launch_bounds__(256) void ln_relu(T* __restrict__ x,
    const float* __restrict__ g, const float* __restrict__ b) {
  const int N = VPT * 256;
  const size_t base = (size_t)blockIdx.x * N;
  const int tid = threadIdx.x, w = tid >> 6, l = tid & 63;
  float v[VPT];
#pragma unroll
  for (int q = 0; q < VPT; ++q) v[q] = (float)x[base + q * 256 + tid];
  float s = 0.0f;
#pragma unroll
  for (int q = 0; q < VPT; ++q) s += v[q];
#pragma unroll
  for (int m = 1; m < 64; m <<= 1) s += __shfl_xor(s, m, 64);
  __shared__ float red[8];
  if (l == 0) red[w] = s;
  __syncthreads();
  float mean = (red[0] + red[1] + red[2] + red[3]) * (1.0f / N);
  float ss = 0.0f;
#pragma unroll
  for (int q = 0; q < VPT; ++q) { float t = v[q] - mean; ss += t * t; }
#pragma unroll
  for (int m = 1; m < 64; m <<= 1) ss += __shfl_xor(ss, m, 64);
  if (l == 0) red[4 + w] = ss;
  __syncthreads();
  float var = (red[4] + red[5] + red[6] + red[7]) * (1.0f / N);
  float rs = 1.0f / sqrtf(var + 1e-5f);
#pragma unroll
  for (int q = 0; q < VPT; ++q) {
    int j = q * 256 + tid;
    float y = (v[q] - mean) * rs * g[j] + b[j];
    x[base + j] = (T)fmaxf(y, 0.0f);
  }
}

// ---------------------------------------------------------------------------
// launch
// ---------------------------------------------------------------------------
extern "C" void kernel_launch(void* const* d_in, const int* in_sizes, int n_in,
                              void* d_out, int out_size, void* d_ws, size_t ws_size,
                              hipStream_t stream) {
  (void)in_sizes; (void)n_in; (void)out_size; (void)ws_size;
  const float* semI  = (const float*)d_in[0];
  const float* colI  = (const float*)d_in[1];
  const float* gw1   = (const float*)d_in[2];
  const float* gb1   = (const float*)d_in[3];
  const float* glng  = (const float*)d_in[4];
  const float* glnb  = (const float*)d_in[5];
  const float* gw2   = (const float*)d_in[6];
  const float* gb2   = (const float*)d_in[7];
  const float* fg    = (const float*)d_in[8];
  const float* fb    = (const float*)d_in[9];
  const float* ew1   = (const float*)d_in[10];
  const float* ew2   = (const float*)d_in[11];
  const float* ew3   = (const float*)d_in[12];
  const float* ew4   = (const float*)d_in[13];
  const float* dw1   = (const float*)d_in[14];
  const float* dw2   = (const float*)d_in[15];
  const float* dw3   = (const float*)d_in[16];
  const float* sw1   = (const float*)d_in[17];
  const float* sb1   = (const float*)d_in[18];
  const float* slng  = (const float*)d_in[19];
  const float* slnb  = (const float*)d_in[20];
  const float* sw2   = (const float*)d_in[21];
  const float* sb2   = (const float*)d_in[22];
  const float* cw1   = (const float*)d_in[23];
  const float* cb1   = (const float*)d_in[24];
  const float* clng  = (const float*)d_in[25];
  const float* clnb  = (const float*)d_in[26];
  const float* cw2   = (const float*)d_in[27];
  const float* cb2   = (const float*)d_in[28];
  const float* cbk   = (const float*)d_in[29];

  float* out = (float*)d_out;
  char* ws = (char*)d_ws;

  // output offsets (floats)
  const size_t OUT_SEM = 0, OUT_COL = 50331648, OUT_ZQ = 54525952,
               OUT_CODES = 58720256, OUT_CB = 58916864, OUT_GATE = 58916866;

  // ws layout (bytes)
  bf16* dec1t = (bf16*)(ws + 0);
  bf16* dec2t = (bf16*)(ws + 16384);
  bf16* dec3t = (bf16*)(ws + 81920);
  bf16* sem1t = (bf16*)(ws + 344064);
  bf16* sem2t = (bf16*)(ws + 1916928);
  bf16* col1t = (bf16*)(ws + 4276224);
  float* cbT  = (float*)(ws + 4538368);
  float* nhn  = (float*)(ws + 4734976);
  const size_t WS_A = 8388608, WS_B = 226492416;
  float* fused  = (float*)(ws + WS_A);
  float* scores = (float*)(ws + WS_A);            // reuses fused after E1
  bf16*  semh   = (bf16*)(ws + WS_A);             // reuses scores after RQ
  float* den = (float*)(ws + WS_B);               // pre-E1 temp
  float* hn  = (float*)(ws + WS_B + 16777216);    // pre-E1 temp
  float* h1  = (float*)(ws + WS_B);
  float* h2  = (float*)(ws + 360710144);
  float* h3  = (float*)(ws + 427819008);
  float* rn  = (float*)(ws + 461373440);
  bf16* zqb  = (bf16*)(ws + WS_B);
  bf16* d1b  = (bf16*)(ws + WS_B + 8388608);
  bf16* d2b  = (bf16*)(ws + WS_B + 25165824);
  bf16* sb   = (bf16*)(ws + WS_B + 58720256);
  float* colh = (float*)(ws + WS_B + 125829120);

  // zero the two loss scalars (d_out is poisoned each launch)
  hipMemsetAsync(out + OUT_CB, 0, 2 * sizeof(float), stream);

  // weight prep
  wconv_t<<<(64 * 128 + 255) / 256, 256, 0, stream>>>(dw1, dec1t, 64, 128);
  wconv_t<<<(128 * 256 + 255) / 256, 256, 0, stream>>>(dw2, dec2t, 128, 256);
  wconv_t<<<(256 * 512 + 255) / 256, 256, 0, stream>>>(dw3, dec3t, 256, 512);
  wconv_t<<<(512 * 1536 + 255) / 256, 256, 0, stream>>>(sw1, sem1t, 512, 1536);
  wconv_t<<<(1536 * 768 + 255) / 256, 256, 0, stream>>>(sw2, sem2t, 1536, 768);
  wconv_t<<<(512 * 256 + 255) / 256, 256, 0, stream>>>(cw1, col1t, 512, 256);
  cbt_k<<<192, 256, 0, stream>>>(cbk, cbT);
  nhn_k<<<3, 256, 0, stream>>>(cbk, nhn);

  // gate network (fp32)
  sgemm128<2><<<dim3(1, 512), 256, 0, stream>>>(colI, gw1, gb1, glng, glnb, hn, 128, 64);
  sgemm64<2><<<512, 256, 0, stream>>>(hn, gw2, gb2, colI, out + OUT_GATE, den, 128);
  fuse_ln<<<4096, 256, 0, stream>>>(semI, den, fg, fb, fused);

  // encoder (fp32)
  sgemm128<0><<<dim3(4, 512), 256, 0, stream>>>(fused, ew1, nullptr, nullptr, nullptr, h1, 512, 832);
  sgemm128<0><<<dim3(2, 512), 256, 0, stream>>>(h1, ew2, nullptr, nullptr, nullptr, h2, 256, 512);
  sgemm128<0><<<dim3(1, 512), 256, 0, stream>>>(h2, ew3, nullptr, nullptr, nullptr, h3, 128, 256);
  sgemm64<0><<<512, 256, 0, stream>>>(h3, ew4, nullptr, nullptr, rn, nullptr, 128);

  // residual quantization (fp32 scores as GEMM + argmax/update)
  sgemm128<1><<<dim3(2, 512), 256, 0, stream>>>(rn, cbT + 0 * 16384, nhn + 0, nullptr, nullptr, scores, 256, 64);
  argupd<0><<<1024, 256, 0, stream>>>(scores, cbk + 0 * 16384, rn, out + OUT_ZQ, out + OUT_CODES, out + OUT_CB, zqb);
  sgemm128<1><<<dim3(2, 512), 256, 0, stream>>>(rn, cbT + 1 * 16384, nhn + 256, nullptr, nullptr, scores, 256, 64);
  argupd<1><<<1024, 256, 0, stream>>>(scores, cbk + 1 * 16384, rn, out + OUT_ZQ, out + OUT_CODES, out + OUT_CB, zqb);
  sgemm128<1><<<dim3(2, 512), 256, 0, stream>>>(rn, cbT + 2 * 16384, nhn + 512, nullptr, nullptr, scores, 256, 64);
  argupd<2><<<1024, 256, 0, stream>>>(scores, cbk + 2 * 16384, rn, out + OUT_ZQ, out + OUT_CODES, out + OUT_CB, zqb);

  // decoder + heads (bf16 MFMA)
  bgemm<0><<<dim3(1, 512), 256, 0, stream>>>(zqb, dec1t, nullptr, d1b, 128, 64);
  bgemm<0><<<dim3(2, 512), 256, 0, stream>>>(d1b, dec2t, nullptr, d2b, 256, 128);
  bgemm<0><<<dim3(4, 512), 256, 0, stream>>>(d2b, dec3t, nullptr, sb, 512, 256);
  bgemm<1><<<dim3(12, 512), 256, 0, stream>>>(sb, sem1t, sb1, semh, 1536, 512);
  ln_relu<6, bf16><<<65536, 256, 0, stream>>>(semh, slng, slnb);
  bgemm<2><<<dim3(6, 512), 256, 0, stream>>>(semh, sem2t, sb2, out + OUT_SEM, 768, 1536);
  bgemm<2><<<dim3(2, 512), 256, 0, stream>>>(sb, col1t, cb1, colh, 256, 512);
  ln_relu<1, float><<<65536, 256, 0, stream>>>(colh, clng, clnb);
  sgemm64<1><<<512, 256, 0, stream>>>(colh, cw2, cb2, nullptr, out + OUT_COL, nullptr, 256);
}

// Round 2
// 2006.862 us; speedup vs baseline: 1.3337x; 1.3337x over previous
//
#include <hip/hip_runtime.h>
#include <hip/hip_bf16.h>
#include <math.h>

typedef __bf16 bf16;
typedef __attribute__((ext_vector_type(8))) __bf16 v8bf;
typedef __attribute__((ext_vector_type(4))) float v4f;
typedef _Float16 f16;
typedef __attribute__((ext_vector_type(8))) _Float16 v8h;
typedef __attribute__((ext_vector_type(4))) _Float16 v4h;

// ---------------------------------------------------------------------------
// small prep kernels
// ---------------------------------------------------------------------------
__global__ void wconv_t(const float* __restrict__ W, bf16* __restrict__ Wt, int Kd, int Nd) {
  int e = blockIdx.x * 256 + threadIdx.x;
  if (e < Kd * Nd) {
    int k = e / Nd, n = e - k * Nd;
    Wt[n * Kd + k] = (bf16)W[e];   // store transposed [N][K] for gemm_bt
  }
}

// fp32 -> 2-plane fp16 split, transposed, pre-scaled by 2048
__global__ void wsplit_t(const float* __restrict__ W, f16* __restrict__ W0,
                         f16* __restrict__ W1, int Kd, int Nd) {
  int e = blockIdx.x * 256 + threadIdx.x;
  if (e < Kd * Nd) {
    int k = e / Nd, n = e - k * Nd;
    float v = W[e] * 2048.0f;
    f16 h0 = (f16)v;
    f16 h1 = (f16)(v - (float)h0);
    W0[n * Kd + k] = h0;
    W1[n * Kd + k] = h1;
  }
}

__global__ void cbt_k(const float* __restrict__ cb, float* __restrict__ cbT) {
  int e = blockIdx.x * 256 + threadIdx.x;   // 3*256*64 total
  if (e < 3 * 256 * 64) {
    int l = e >> 14, rem = e & 16383;
    int c = rem >> 6, d = rem & 63;
    cbT[l * 16384 + d * 256 + c] = cb[e];   // [l][d][c]
  }
}

__global__ void nhn_k(const float* __restrict__ cb, float* __restrict__ nhn) {
  int l = blockIdx.x, c = threadIdx.x;      // grid 3 x 256
  const float* p = cb + l * 16384 + c * 64;
  double s = 0.0;
  for (int d = 0; d < 64; ++d) { double v = (double)p[d]; s += v * v; }
  nhn[l * 256 + c] = (float)(-0.5 * s);
}

// ---------------------------------------------------------------------------
// fp32 GEMM, 128x128 tile, BK=32, 8x8 per thread.
// EPI: 0 = SiLU->f32, 1 = +bias->f32, 2 = +bias, LN(128), ReLU -> f32 (needs gridDim.x==1,N==128)
// ---------------------------------------------------------------------------
template <int EPI>
__global__ __launch_bounds__(256, 2) void sgemm128(
    const float* __restrict__ A, const float* __restrict__ W,
    const float* __restrict__ bias, const float* __restrict__ lng,
    const float* __restrict__ lnb, float* __restrict__ C, int N, int Kd) {
  __shared__ float As[32][132];   // [k][m], padded
  __shared__ float Bs[32][128];   // [k][n]
  const int tid = threadIdx.x;
  const int w = tid >> 6, l = tid & 63;
  int tx, ty;
  if (EPI == 2) { tx = tid & 15; ty = tid >> 4; }
  else { tx = ((w & 1) << 3) | (l & 7); ty = ((w >> 1) << 3) | (l >> 3); }
  const int bm = blockIdx.y << 7, bn = blockIdx.x << 7;

  float acc[8][8];
#pragma unroll
  for (int i = 0; i < 8; ++i)
#pragma unroll
    for (int j = 0; j < 8; ++j) acc[i][j] = 0.0f;

  for (int k0 = 0; k0 < Kd; k0 += 32) {
    __syncthreads();
#pragma unroll
    for (int jj = 0; jj < 4; ++jj) {
      int p = tid + 256 * jj;
      int arow = p >> 3, aks = (p & 7) << 2;
      float4 v = *(const float4*)(A + (size_t)(bm + arow) * Kd + k0 + aks);
      As[aks][arow] = v.x; As[aks + 1][arow] = v.y;
      As[aks + 2][arow] = v.z; As[aks + 3][arow] = v.w;
      int bk = p >> 5, bns = (p & 31) << 2;
      float4 u = *(const float4*)(W + (size_t)(k0 + bk) * N + bn + bns);
      *(float4*)(&Bs[bk][bns]) = u;
    }
    __syncthreads();
    float cacc[8][8];
#pragma unroll
    for (int i = 0; i < 8; ++i)
#pragma unroll
      for (int j = 0; j < 8; ++j) cacc[i][j] = 0.0f;
#pragma unroll 4
    for (int kk = 0; kk < 32; ++kk) {
      float a[8], b[8];
#pragma unroll
      for (int i = 0; i < 8; ++i) a[i] = As[kk][ty * 8 + i];
#pragma unroll
      for (int j = 0; j < 8; ++j) b[j] = Bs[kk][tx * 8 + j];
#pragma unroll
      for (int i = 0; i < 8; ++i)
#pragma unroll
        for (int j = 0; j < 8; ++j) cacc[i][j] = fmaf(a[i], b[j], cacc[i][j]);
    }
#pragma unroll
    for (int i = 0; i < 8; ++i)
#pragma unroll
      for (int j = 0; j < 8; ++j) acc[i][j] += cacc[i][j];
  }

  const int colb = bn + tx * 8;
  if (EPI == 0) {
#pragma unroll
    for (int i = 0; i < 8; ++i) {
      int row = bm + ty * 8 + i;
      float o[8];
#pragma unroll
      for (int j = 0; j < 8; ++j) { float v = acc[i][j]; o[j] = v / (1.0f + expf(-v)); }
      *(float4*)(C + (size_t)row * N + colb) = make_float4(o[0], o[1], o[2], o[3]);
      *(float4*)(C + (size_t)row * N + colb + 4) = make_float4(o[4], o[5], o[6], o[7]);
    }
  } else if (EPI == 1) {
    float bb[8];
#pragma unroll
    for (int j = 0; j < 8; ++j) bb[j] = bias[colb + j];
#pragma unroll
    for (int i = 0; i < 8; ++i) {
      int row = bm + ty * 8 + i;
      float o[8];
#pragma unroll
      for (int j = 0; j < 8; ++j) o[j] = acc[i][j] + bb[j];
      *(float4*)(C + (size_t)row * N + colb) = make_float4(o[0], o[1], o[2], o[3]);
      *(float4*)(C + (size_t)row * N + colb + 4) = make_float4(o[4], o[5], o[6], o[7]);
    }
  } else {
    float bb[8], lg[8], lb[8];
#pragma unroll
    for (int j = 0; j < 8; ++j) { bb[j] = bias[colb + j]; lg[j] = lng[colb + j]; lb[j] = lnb[colb + j]; }
#pragma unroll
    for (int i = 0; i < 8; ++i) {
      int row = bm + ty * 8 + i;
      float v[8]; float s = 0.0f;
#pragma unroll
      for (int j = 0; j < 8; ++j) { v[j] = acc[i][j] + bb[j]; s += v[j]; }
      s += __shfl_xor(s, 1); s += __shfl_xor(s, 2); s += __shfl_xor(s, 4); s += __shfl_xor(s, 8);
      float mean = s * (1.0f / 128.0f);
      float ss = 0.0f;
#pragma unroll
      for (int j = 0; j < 8; ++j) { float t = v[j] - mean; ss += t * t; }
      ss += __shfl_xor(ss, 1); ss += __shfl_xor(ss, 2); ss += __shfl_xor(ss, 4); ss += __shfl_xor(ss, 8);
      float rs = 1.0f / sqrtf(ss * (1.0f / 128.0f) + 1e-5f);
      float o[8];
#pragma unroll
      for (int j = 0; j < 8; ++j) o[j] = fmaxf((v[j] - mean) * rs * lg[j] + lb[j], 0.0f);
      *(float4*)(C + (size_t)row * N + colb) = make_float4(o[0], o[1], o[2], o[3]);
      *(float4*)(C + (size_t)row * N + colb + 4) = make_float4(o[4], o[5], o[6], o[7]);
    }
  }
}

// ---------------------------------------------------------------------------
// fp32 GEMM, 128x64 tile (N fixed 64), BK=32, 8x4 per thread.
// EPI: 0 = l2norm row -> C, 1 = +bias -> C, 2 = gate (sigmoid->C, gate*aux->C2)
// ---------------------------------------------------------------------------
template <int EPI>
__global__ __launch_bounds__(256, 2) void sgemm64(
    const float* __restrict__ A, const float* __restrict__ W,
    const float* __restrict__ bias, const float* __restrict__ aux,
    float* __restrict__ C, float* __restrict__ C2, int Kd) {
  __shared__ float As[32][132];
  __shared__ float Bs[32][64];
  const int tid = threadIdx.x;
  const int tx = tid & 15, ty = tid >> 4;
  const int bm = blockIdx.x << 7;

  float acc[8][4];
#pragma unroll
  for (int i = 0; i < 8; ++i)
#pragma unroll
    for (int j = 0; j < 4; ++j) acc[i][j] = 0.0f;

  for (int k0 = 0; k0 < Kd; k0 += 32) {
    __syncthreads();
#pragma unroll
    for (int jj = 0; jj < 4; ++jj) {
      int p = tid + 256 * jj;
      int arow = p >> 3, aks = (p & 7) << 2;
      float4 v = *(const float4*)(A + (size_t)(bm + arow) * Kd + k0 + aks);
      As[aks][arow] = v.x; As[aks + 1][arow] = v.y;
      As[aks + 2][arow] = v.z; As[aks + 3][arow] = v.w;
    }
#pragma unroll
    for (int jj = 0; jj < 2; ++jj) {
      int p = tid + 256 * jj;
      int bk = p >> 4, bns = (p & 15) << 2;
      float4 u = *(const float4*)(W + (size_t)(k0 + bk) * 64 + bns);
      *(float4*)(&Bs[bk][bns]) = u;
    }
    __syncthreads();
    float cacc[8][4];
#pragma unroll
    for (int i = 0; i < 8; ++i)
#pragma unroll
      for (int j = 0; j < 4; ++j) cacc[i][j] = 0.0f;
#pragma unroll 4
    for (int kk = 0; kk < 32; ++kk) {
      float a[8], b[4];
#pragma unroll
      for (int i = 0; i < 8; ++i) a[i] = As[kk][ty * 8 + i];
#pragma unroll
      for (int j = 0; j < 4; ++j) b[j] = Bs[kk][tx * 4 + j];
#pragma unroll
      for (int i = 0; i < 8; ++i)
#pragma unroll
        for (int j = 0; j < 4; ++j) cacc[i][j] = fmaf(a[i], b[j], cacc[i][j]);
    }
#pragma unroll
    for (int i = 0; i < 8; ++i)
#pragma unroll
      for (int j = 0; j < 4; ++j) acc[i][j] += cacc[i][j];
  }

  const int colb = tx * 4;
  if (EPI == 0) {           // l2norm(z) -> rn
#pragma unroll
    for (int i = 0; i < 8; ++i) {
      int row = bm + ty * 8 + i;
      float ss = 0.0f;
#pragma unroll
      for (int j = 0; j < 4; ++j) ss += acc[i][j] * acc[i][j];
      ss += __shfl_xor(ss, 1); ss += __shfl_xor(ss, 2); ss += __shfl_xor(ss, 4); ss += __shfl_xor(ss, 8);
      float nrm = fmaxf(sqrtf(ss), 1e-12f);
      *(float4*)(C + (size_t)row * 64 + colb) =
          make_float4(acc[i][0] / nrm, acc[i][1] / nrm, acc[i][2] / nrm, acc[i][3] / nrm);
    }
  } else if (EPI == 1) {
    float bb[4];
#pragma unroll
    for (int j = 0; j < 4; ++j) bb[j] = bias[colb + j];
#pragma unroll
    for (int i = 0; i < 8; ++i) {
      int row = bm + ty * 8 + i;
      *(float4*)(C + (size_t)row * 64 + colb) =
          make_float4(acc[i][0] + bb[0], acc[i][1] + bb[1], acc[i][2] + bb[2], acc[i][3] + bb[3]);
    }
  } else {                  // gate: sigmoid -> C (gate_values), gate*collab -> C2 (denoised)
    float bb[4];
#pragma unroll
    for (int j = 0; j < 4; ++j) bb[j] = bias[colb + j];
#pragma unroll
    for (int i = 0; i < 8; ++i) {
      int row = bm + ty * 8 + i;
      float4 av = *(const float4*)(aux + (size_t)row * 64 + colb);
      float g[4];
#pragma unroll
      for (int j = 0; j < 4; ++j) g[j] = 1.0f / (1.0f + expf(-(acc[i][j] + bb[j])));
      *(float4*)(C + (size_t)row * 64 + colb) = make_float4(g[0], g[1], g[2], g[3]);
      *(float4*)(C2 + (size_t)row * 64 + colb) =
          make_float4(g[0] * av.x, g[1] * av.y, g[2] * av.z, g[3] * av.w);
    }
  }
}

// ---------------------------------------------------------------------------
// fusion layernorm over 832 = concat(sem 768, denoised 64); wave per row
// ---------------------------------------------------------------------------
__global__ __launch_bounds__(256) void fuse_ln(
    const float* __restrict__ sem, const float* __restrict__ den,
    const float* __restrict__ fg, const float* __restrict__ fb,
    float* __restrict__ fused) {
  const int w = threadIdx.x >> 6, l = threadIdx.x & 63;
  float fgv[13], fbv[13];
#pragma unroll
  for (int q = 0; q < 12; ++q) { fgv[q] = fg[q * 64 + l]; fbv[q] = fb[q * 64 + l]; }
  fgv[12] = fg[768 + l]; fbv[12] = fb[768 + l];
  for (int it = 0; it < 4; ++it) {
    int r = (blockIdx.x * 4 + w) * 4 + it;
    float sv[12];
#pragma unroll
    for (int q = 0; q < 12; ++q) sv[q] = sem[(size_t)r * 768 + q * 64 + l];
    float dv = den[(size_t)r * 64 + l];
    float s = dv;
#pragma unroll
    for (int q = 0; q < 12; ++q) s += sv[q];
#pragma unroll
    for (int m = 1; m < 64; m <<= 1) s += __shfl_xor(s, m, 64);
    float mean = s * (1.0f / 832.0f);
    float t0 = dv - mean;
    float ss = t0 * t0;
#pragma unroll
    for (int q = 0; q < 12; ++q) { float t = sv[q] - mean; ss += t * t; }
#pragma unroll
    for (int m = 1; m < 64; m <<= 1) ss += __shfl_xor(ss, m, 64);
    float sc = 1.0f / sqrtf(ss * (1.0f / 832.0f) + 1e-5f);
#pragma unroll
    for (int q = 0; q < 12; ++q)
      fused[(size_t)r * 832 + q * 64 + l] = (sv[q] - mean) * sc * fgv[q] + fbv[q];
    fused[(size_t)r * 832 + 768 + l] = t0 * sc * fgv[12] + fbv[12];
  }
}

// ---------------------------------------------------------------------------
// RQ argmax + update; wave per row, 16 rows/wave
// ---------------------------------------------------------------------------
template <int LAYER>
__global__ __launch_bounds__(256) void argupd(
    const float* __restrict__ scores, const float* __restrict__ cbl,
    float* __restrict__ rn, float* __restrict__ zq, float* __restrict__ codes,
    float* __restrict__ loss, bf16* __restrict__ zqb) {
  const int w = threadIdx.x >> 6, l = threadIdx.x & 63;
  const int base = (blockIdx.x * 4 + w) * 16;
  float lacc = 0.0f;
  for (int it = 0; it < 16; ++it) {
    int r = base + it;
    float4 s4 = *(const float4*)(scores + (size_t)r * 256 + l * 4);
    float bs = s4.x; int bi = l * 4;
    if (s4.y > bs) { bs = s4.y; bi = l * 4 + 1; }
    if (s4.z > bs) { bs = s4.z; bi = l * 4 + 2; }
    if (s4.w > bs) { bs = s4.w; bi = l * 4 + 3; }
#pragma unroll
    for (int m = 1; m < 64; m <<= 1) {
      float os = __shfl_xor(bs, m, 64);
      int oi = __shfl_xor(bi, m, 64);
      if (os > bs || (os == bs && oi < bi)) { bs = os; bi = oi; }
    }
    float e = cbl[bi * 64 + l];
    float rl = rn[(size_t)r * 64 + l];
    float emr = e - rl;
    float zql = rl + emr;          // straight-through forward value, ref rounding order
    lacc += emr * emr;
    if (l == 0) codes[r * 3 + LAYER] = (float)bi;
    if (LAYER == 0) {
      zq[(size_t)r * 64 + l] = zql;
    } else if (LAYER == 1) {
      zq[(size_t)r * 64 + l] += zql;
    } else {
      float tot = zq[(size_t)r * 64 + l] + zql;
      zq[(size_t)r * 64 + l] = tot;
      zqb[(size_t)r * 64 + l] = (bf16)tot;
    }
    if (LAYER < 2) {
      float rnew = rl - zql;
      float ss = rnew * rnew;
#pragma unroll
      for (int m = 1; m < 64; m <<= 1) ss += __shfl_xor(ss, m, 64);
      float nrm = fmaxf(sqrtf(ss), 1e-12f);
      rn[(size_t)r * 64 + l] = rnew / nrm;
    }
  }
#pragma unroll
  for (int m = 1; m < 64; m <<= 1) lacc += __shfl_xor(lacc, m, 64);
  if (l == 0) {
    float v = lacc * (1.0f / 4194304.0f);   // 1/(65536*64), exact pow2
    atomicAdd(loss, v);
    atomicAdd(loss + 1, v);
  }
}

// ---------------------------------------------------------------------------
// async global->LDS helper
// ---------------------------------------------------------------------------
typedef __attribute__((address_space(3))) void lds_void_t;
typedef __attribute__((address_space(1))) const void gbl_void_t;
__device__ __forceinline__ void gl_lds16(const void* g, void* l) {
  __builtin_amdgcn_global_load_lds((gbl_void_t*)g, (lds_void_t*)l, 16, 0, 0);
}

// ---------------------------------------------------------------------------
// fp32-accurate GEMM via 2-way fp16 split + 3 MFMA products (m97 structure).
// A fp32 (split on the fly, x256); W pre-split fp16 planes [N][K] (x2048).
// Epilogue: SiLU(acc * 2^-19) -> fp32.
// Added noise ~3e-8 abs (split residual 2^-24, dropped a1*b1 ~2^-25 RMS) --
// below fp32 reorder noise; safe for the codes argmax.
// ---------------------------------------------------------------------------
__global__ __launch_bounds__(256, 3) void hgemm3(
    const float* __restrict__ A, const f16* __restrict__ W0,
    const f16* __restrict__ W1, float* __restrict__ C, int N, int Kd) {
  __shared__ __align__(16) f16 As0[128 * 32];
  __shared__ __align__(16) f16 As1[128 * 32];
  __shared__ __align__(16) f16 Bs0[128 * 32];
  __shared__ __align__(16) f16 Bs1[128 * 32];
  const int tid = threadIdx.x;
  const int w = tid >> 6, l = tid & 63;
  const int bm = blockIdx.y << 7, bn = blockIdx.x << 7;
  const int wm = (w >> 1) << 6, wn = (w & 1) << 6;

  v4f acc[4][4];
  v4f z4 = {0.0f, 0.0f, 0.0f, 0.0f};
#pragma unroll
  for (int i = 0; i < 4; ++i)
#pragma unroll
    for (int j = 0; j < 4; ++j) acc[i][j] = z4;

  const int srow = (w << 5) + (l >> 2);
  const int skc = (l & 3) << 3;                 // halves
  const f16* gb0 = W0 + (size_t)(bn + srow) * Kd + skc;
  const f16* gb1 = W1 + (size_t)(bn + srow) * Kd + skc;
  char* lb0 = (char*)Bs0 + (w << 11);
  char* lb1 = (char*)Bs1 + (w << 11);

  for (int k0 = 0; k0 < Kd; k0 += 32) {
    __syncthreads();
    // B planes: async direct-to-LDS (layout [row][k], 64 B/row)
    gl_lds16(gb0 + k0, lb0);
    gl_lds16(gb0 + (size_t)16 * Kd + k0, lb0 + 1024);
    gl_lds16(gb1 + k0, lb1);
    gl_lds16(gb1 + (size_t)16 * Kd + k0, lb1 + 1024);
    // A: load fp32, scale x256, split into two fp16 planes
#pragma unroll
    for (int jj = 0; jj < 4; ++jj) {
      int idx = tid + 256 * jj;
      int row = idx >> 3, kq = (idx & 7) << 2;
      float4 v = *(const float4*)(A + (size_t)(bm + row) * Kd + k0 + kq);
      v4h h0, h1;
      float x;
      x = v.x * 256.0f; h0.x = (f16)x; h1.x = (f16)(x - (float)h0.x);
      x = v.y * 256.0f; h0.y = (f16)x; h1.y = (f16)(x - (float)h0.y);
      x = v.z * 256.0f; h0.z = (f16)x; h1.z = (f16)(x - (float)h0.z);
      x = v.w * 256.0f; h0.w = (f16)x; h1.w = (f16)(x - (float)h0.w);
      *(v4h*)(&As0[row * 32 + kq]) = h0;
      *(v4h*)(&As1[row * 32 + kq]) = h1;
    }
    __syncthreads();
    v8h a0f[4], a1f[4], b0f[4], b1f[4];
#pragma unroll
    for (int f = 0; f < 4; ++f) {
      int ro = (wm + f * 16 + (l & 15)) * 32 + ((l >> 4) << 3);
      int co = (wn + f * 16 + (l & 15)) * 32 + ((l >> 4) << 3);
      a0f[f] = *(const v8h*)(As0 + ro);
      a1f[f] = *(const v8h*)(As1 + ro);
      b0f[f] = *(const v8h*)(Bs0 + co);
      b1f[f] = *(const v8h*)(Bs1 + co);
    }
#pragma unroll
    for (int mf = 0; mf < 4; ++mf)
#pragma unroll
      for (int nf = 0; nf < 4; ++nf) {
        acc[mf][nf] = __builtin_amdgcn_mfma_f32_16x16x32_f16(a0f[mf], b1f[nf], acc[mf][nf], 0, 0, 0);
        acc[mf][nf] = __builtin_amdgcn_mfma_f32_16x16x32_f16(a1f[mf], b0f[nf], acc[mf][nf], 0, 0, 0);
        acc[mf][nf] = __builtin_amdgcn_mfma_f32_16x16x32_f16(a0f[mf], b0f[nf], acc[mf][nf], 0, 0, 0);
      }
  }

  const float sc = 1.0f / (256.0f * 2048.0f);   // 2^-19 exact
  const int cbase = bn + wn + (l & 15);
#pragma unroll
  for (int mf = 0; mf < 4; ++mf) {
#pragma unroll
    for (int i = 0; i < 4; ++i) {
      int row = bm + wm + mf * 16 + ((l >> 4) << 2) + i;
#pragma unroll
      for (int nf = 0; nf < 4; ++nf) {
        int col = cbase + nf * 16;
        float v = acc[mf][nf][i] * sc;
        v = v / (1.0f + expf(-v));              // SiLU, precision path
        C[(size_t)row * N + col] = v;
      }
    }
  }
}

// ---------------------------------------------------------------------------
// bf16 MFMA GEMM (gemm_bt, m97 structure): 128x128 tile, BK=32, global_load_lds
// EPI: 0 = SiLU->bf16, 1 = +bias->bf16, 2 = +bias->f32
// ---------------------------------------------------------------------------
template <int EPI>
__global__ __launch_bounds__(256, 3) void bgemm(
    const bf16* __restrict__ A, const bf16* __restrict__ Wt,
    const float* __restrict__ bias, void* __restrict__ Cv, int N, int Kd) {
  __shared__ __align__(16) bf16 As[128 * 32];
  __shared__ __align__(16) bf16 Bs[128 * 32];
  const int tid = threadIdx.x;
  const int w = tid >> 6, l = tid & 63;
  const int bm = blockIdx.y << 7, bn = blockIdx.x << 7;
  const int wm = (w >> 1) << 6, wn = (w & 1) << 6;

  v4f acc[4][4];
  v4f z4 = {0.0f, 0.0f, 0.0f, 0.0f};
#pragma unroll
  for (int i = 0; i < 4; ++i)
#pragma unroll
    for (int j = 0; j < 4; ++j) acc[i][j] = z4;

  const int srow = (w << 5) + (l >> 2);
  const int skc = (l & 3) << 3;
  const bf16* ga0 = A + (size_t)(bm + srow) * Kd + skc;
  const bf16* gb0 = Wt + (size_t)(bn + srow) * Kd + skc;
  char* la0 = (char*)As + (w << 11);
  char* lb0 = (char*)Bs + (w << 11);

  for (int k0 = 0; k0 < Kd; k0 += 32) {
    __syncthreads();
    gl_lds16(ga0 + k0, la0);
    gl_lds16(ga0 + (size_t)16 * Kd + k0, la0 + 1024);
    gl_lds16(gb0 + k0, lb0);
    gl_lds16(gb0 + (size_t)16 * Kd + k0, lb0 + 1024);
    __syncthreads();
    v8bf af[4], bfr[4];
#pragma unroll
    for (int f = 0; f < 4; ++f) {
      af[f] = *(const v8bf*)(As + (wm + f * 16 + (l & 15)) * 32 + ((l >> 4) << 3));
      bfr[f] = *(const v8bf*)(Bs + (wn + f * 16 + (l & 15)) * 32 + ((l >> 4) << 3));
    }
#pragma unroll
    for (int mf = 0; mf < 4; ++mf)
#pragma unroll
      for (int nf = 0; nf < 4; ++nf)
        acc[mf][nf] = __builtin_amdgcn_mfma_f32_16x16x32_bf16(af[mf], bfr[nf], acc[mf][nf], 0, 0, 0);
  }

  const int cbase = bn + wn + (l & 15);
  float bb[4];
  if (EPI != 0) {
#pragma unroll
    for (int nf = 0; nf < 4; ++nf) bb[nf] = bias[cbase + nf * 16];
  }
#pragma unroll
  for (int mf = 0; mf < 4; ++mf) {
#pragma unroll
    for (int i = 0; i < 4; ++i) {
      int row = bm + wm + mf * 16 + ((l >> 4) << 2) + i;
#pragma unroll
      for (int nf = 0; nf < 4; ++nf) {
        int col = cbase + nf * 16;
        float v = acc[mf][nf][i];
        if (EPI == 0) {
          v = v / (1.0f + __expf(-v));
          ((bf16*)Cv)[(size_t)row * N + col] = (bf16)v;
        } else if (EPI == 1) {
          v += bb[nf];
          ((bf16*)Cv)[(size_t)row * N + col] = (bf16)v;
        } else {
          v += bb[nf];
          ((float*)Cv)[(size_t)row * N + col] = v;
        }
      }
    }
  }
}

// ---------------------------------------------------------------------------
// row layernorm + relu, in place; block per row
// ---------------------------------------------------------------------------
template <int VPT, typename T>
__global__ __launch_bounds__(256) void ln_relu(T* __restrict__ x,
    const float* __restrict__ g, const float* __restrict__ b) {
  const int N = VPT * 256;
  const size_t base = (size_t)blockIdx.x * N;
  const int tid = threadIdx.x, w = tid >> 6, l = tid & 63;
  float v[VPT];
#pragma unroll
  for (int q = 0; q < VPT; ++q) v[q] = (float)x[base + q * 256 + tid];
  float s = 0.0f;
#pragma unroll
  for (int q = 0; q < VPT; ++q) s += v[q];
#pragma unroll
  for (int m = 1; m < 64; m <<= 1) s += __shfl_xor(s, m, 64);
  __shared__ float red[8];
  if (l == 0) red[w] = s;
  __syncthreads();
  float mean = (red[0] + red[1] + red[2] + red[3]) * (1.0f / N);
  float ss = 0.0f;
#pragma unroll
  for (int q = 0; q < VPT; ++q) { float t = v[q] - mean; ss += t * t; }
#pragma unroll
  for (int m = 1; m < 64; m <<= 1) ss += __shfl_xor(ss, m, 64);
  if (l == 0) red[4 + w] = ss;
  __syncthreads();
  float var = (red[4] + red[5] + red[6] + red[7]) * (1.0f / N);
  float rs = 1.0f / sqrtf(var + 1e-5f);
#pragma unroll
  for (int q = 0; q < VPT; ++q) {
    int j = q * 256 + tid;
    float y = (v[q] - mean) * rs * g[j] + b[j];
    x[base + j] = (T)fmaxf(y, 0.0f);
  }
}

// ---------------------------------------------------------------------------
// launch
// ---------------------------------------------------------------------------
extern "C" void kernel_launch(void* const* d_in, const int* in_sizes, int n_in,
                              void* d_out, int out_size, void* d_ws, size_t ws_size,
                              hipStream_t stream) {
  (void)in_sizes; (void)n_in; (void)out_size; (void)ws_size;
  const float* semI  = (const float*)d_in[0];
  const float* colI  = (const float*)d_in[1];
  const float* gw1   = (const float*)d_in[2];
  const float* gb1   = (const float*)d_in[3];
  const float* glng  = (const float*)d_in[4];
  const float* glnb  = (const float*)d_in[5];
  const float* gw2   = (const float*)d_in[6];
  const float* gb2   = (const float*)d_in[7];
  const float* fg    = (const float*)d_in[8];
  const float* fb    = (const float*)d_in[9];
  const float* ew1   = (const float*)d_in[10];
  const float* ew2   = (const float*)d_in[11];
  const float* ew3   = (const float*)d_in[12];
  const float* ew4   = (const float*)d_in[13];
  const float* dw1   = (const float*)d_in[14];
  const float* dw2   = (const float*)d_in[15];
  const float* dw3   = (const float*)d_in[16];
  const float* sw1   = (const float*)d_in[17];
  const float* sb1   = (const float*)d_in[18];
  const float* slng  = (const float*)d_in[19];
  const float* slnb  = (const float*)d_in[20];
  const float* sw2   = (const float*)d_in[21];
  const float* sb2   = (const float*)d_in[22];
  const float* cw1   = (const float*)d_in[23];
  const float* cb1   = (const float*)d_in[24];
  const float* clng  = (const float*)d_in[25];
  const float* clnb  = (const float*)d_in[26];
  const float* cw2   = (const float*)d_in[27];
  const float* cb2   = (const float*)d_in[28];
  const float* cbk   = (const float*)d_in[29];

  float* out = (float*)d_out;
  char* ws = (char*)d_ws;

  // output offsets (floats)
  const size_t OUT_SEM = 0, OUT_COL = 50331648, OUT_ZQ = 54525952,
               OUT_CODES = 58720256, OUT_CB = 58916864, OUT_GATE = 58916866;

  // ws layout (bytes)
  bf16* dec1t = (bf16*)(ws + 0);
  bf16* dec2t = (bf16*)(ws + 16384);
  bf16* dec3t = (bf16*)(ws + 81920);
  bf16* sem1t = (bf16*)(ws + 344064);
  bf16* sem2t = (bf16*)(ws + 1916928);
  bf16* col1t = (bf16*)(ws + 4276224);
  float* cbT  = (float*)(ws + 4538368);
  float* nhn  = (float*)(ws + 4734976);
  f16* e1w0   = (f16*)(ws + 4739072);
  f16* e1w1   = (f16*)(ws + 5591040);
  f16* e2w0   = (f16*)(ws + 6443008);
  f16* e2w1   = (f16*)(ws + 6705152);
  f16* e3w0   = (f16*)(ws + 6967296);
  f16* e3w1   = (f16*)(ws + 7032832);
  const size_t WS_A = 8388608, WS_B = 226492416;
  float* fused  = (float*)(ws + WS_A);
  float* scores = (float*)(ws + WS_A);            // reuses fused after E1
  bf16*  semh   = (bf16*)(ws + WS_A);             // reuses scores after RQ
  float* den = (float*)(ws + WS_B);               // pre-E1 temp
  float* hn  = (float*)(ws + WS_B + 16777216);    // pre-E1 temp
  float* h1  = (float*)(ws + WS_B);
  float* h2  = (float*)(ws + 360710144);
  float* h3  = (float*)(ws + 427819008);
  float* rn  = (float*)(ws + 461373440);
  bf16* zqb  = (bf16*)(ws + WS_B);
  bf16* d1b  = (bf16*)(ws + WS_B + 8388608);
  bf16* d2b  = (bf16*)(ws + WS_B + 25165824);
  bf16* sb   = (bf16*)(ws + WS_B + 58720256);
  float* colh = (float*)(ws + WS_B + 125829120);

  // zero the two loss scalars (d_out is poisoned each launch)
  hipMemsetAsync(out + OUT_CB, 0, 2 * sizeof(float), stream);

  // weight prep
  wconv_t<<<(64 * 128 + 255) / 256, 256, 0, stream>>>(dw1, dec1t, 64, 128);
  wconv_t<<<(128 * 256 + 255) / 256, 256, 0, stream>>>(dw2, dec2t, 128, 256);
  wconv_t<<<(256 * 512 + 255) / 256, 256, 0, stream>>>(dw3, dec3t, 256, 512);
  wconv_t<<<(512 * 1536 + 255) / 256, 256, 0, stream>>>(sw1, sem1t, 512, 1536);
  wconv_t<<<(1536 * 768 + 255) / 256, 256, 0, stream>>>(sw2, sem2t, 1536, 768);
  wconv_t<<<(512 * 256 + 255) / 256, 256, 0, stream>>>(cw1, col1t, 512, 256);
  wsplit_t<<<(832 * 512 + 255) / 256, 256, 0, stream>>>(ew1, e1w0, e1w1, 832, 512);
  wsplit_t<<<(512 * 256 + 255) / 256, 256, 0, stream>>>(ew2, e2w0, e2w1, 512, 256);
  wsplit_t<<<(256 * 128 + 255) / 256, 256, 0, stream>>>(ew3, e3w0, e3w1, 256, 128);
  cbt_k<<<192, 256, 0, stream>>>(cbk, cbT);
  nhn_k<<<3, 256, 0, stream>>>(cbk, nhn);

  // gate network (fp32)
  sgemm128<2><<<dim3(1, 512), 256, 0, stream>>>(colI, gw1, gb1, glng, glnb, hn, 128, 64);
  sgemm64<2><<<512, 256, 0, stream>>>(hn, gw2, gb2, colI, out + OUT_GATE, den, 128);
  fuse_ln<<<4096, 256, 0, stream>>>(semI, den, fg, fb, fused);

  // encoder (fp32-accurate via fp16 split MFMA)
  hgemm3<<<dim3(4, 512), 256, 0, stream>>>(fused, e1w0, e1w1, h1, 512, 832);
  hgemm3<<<dim3(2, 512), 256, 0, stream>>>(h1, e2w0, e2w1, h2, 256, 512);
  hgemm3<<<dim3(1, 512), 256, 0, stream>>>(h2, e3w0, e3w1, h3, 128, 256);
  sgemm64<0><<<512, 256, 0, stream>>>(h3, ew4, nullptr, nullptr, rn, nullptr, 128);

  // residual quantization (fp32 scores as GEMM + argmax/update)
  sgemm128<1><<<dim3(2, 512), 256, 0, stream>>>(rn, cbT + 0 * 16384, nhn + 0, nullptr, nullptr, scores, 256, 64);
  argupd<0><<<1024, 256, 0, stream>>>(scores, cbk + 0 * 16384, rn, out + OUT_ZQ, out + OUT_CODES, out + OUT_CB, zqb);
  sgemm128<1><<<dim3(2, 512), 256, 0, stream>>>(rn, cbT + 1 * 16384, nhn + 256, nullptr, nullptr, scores, 256, 64);
  argupd<1><<<1024, 256, 0, stream>>>(scores, cbk + 1 * 16384, rn, out + OUT_ZQ, out + OUT_CODES, out + OUT_CB, zqb);
  sgemm128<1><<<dim3(2, 512), 256, 0, stream>>>(rn, cbT + 2 * 16384, nhn + 512, nullptr, nullptr, scores, 256, 64);
  argupd<2><<<1024, 256, 0, stream>>>(scores, cbk + 2 * 16384, rn, out + OUT_ZQ, out + OUT_CODES, out + OUT_CB, zqb);

  // decoder + heads (bf16 MFMA)
  bgemm<0><<<dim3(1, 512), 256, 0, stream>>>(zqb, dec1t, nullptr, d1b, 128, 64);
  bgemm<0><<<dim3(2, 512), 256, 0, stream>>>(d1b, dec2t, nullptr, d2b, 256, 128);
  bgemm<0><<<dim3(4, 512), 256, 0, stream>>>(d2b, dec3t, nullptr, sb, 512, 256);
  bgemm<1><<<dim3(12, 512), 256, 0, stream>>>(sb, sem1t, sb1, semh, 1536, 512);
  ln_relu<6, bf16><<<65536, 256, 0, stream>>>(semh, slng, slnb);
  bgemm<2><<<dim3(6, 512), 256, 0, stream>>>(semh, sem2t, sb2, out + OUT_SEM, 768, 1536);
  bgemm<2><<<dim3(2, 512), 256, 0, stream>>>(sb, col1t, cb1, colh, 256, 512);
  ln_relu<1, float><<<65536, 256, 0, stream>>>(colh, clng, clnb);
  sgemm64<1><<<512, 256, 0, stream>>>(colh, cw2, cb2, nullptr, out + OUT_COL, nullptr, 256);
}

// Round 3
// 1989.789 us; speedup vs baseline: 1.3451x; 1.0086x over previous
//
#include <hip/hip_runtime.h>
#include <hip/hip_bf16.h>
#include <math.h>

typedef __bf16 bf16;
typedef __attribute__((ext_vector_type(8))) __bf16 v8bf;
typedef __attribute__((ext_vector_type(4))) float v4f;
typedef _Float16 f16;
typedef __attribute__((ext_vector_type(8))) _Float16 v8h;
typedef __attribute__((ext_vector_type(4))) _Float16 v4h;

// XCD-ownership block swizzle: HW round-robins linear block ids across 8 XCDs
// (id%8). Remap so each XCD owns a contiguous bm slab and sweeps bn fastest ->
// each A row-tile lives in exactly one XCD's L2 (fetched from HBM once).
// Requires gridDim.y % 8 == 0. Perf heuristic only; correctness independent.
__device__ __forceinline__ void xcd_swizzle(int& bm, int& bn) {
  const int nx = gridDim.x;
  const int id = blockIdx.y * nx + blockIdx.x;
  const int slot = id >> 3;
  const int row_in = slot / nx;
  const int bmi = (id & 7) * (gridDim.y >> 3) + row_in;
  const int bni = slot - row_in * nx;
  bm = bmi << 7; bn = bni << 7;
}

// ---------------------------------------------------------------------------
// small prep kernels
// ---------------------------------------------------------------------------
__global__ void wconv_t(const float* __restrict__ W, bf16* __restrict__ Wt, int Kd, int Nd) {
  int e = blockIdx.x * 256 + threadIdx.x;
  if (e < Kd * Nd) {
    int k = e / Nd, n = e - k * Nd;
    Wt[n * Kd + k] = (bf16)W[e];   // store transposed [N][K] for gemm_bt
  }
}

// fp32 -> 2-plane fp16 split, transposed, pre-scaled by 2048
__global__ void wsplit_t(const float* __restrict__ W, f16* __restrict__ W0,
                         f16* __restrict__ W1, int Kd, int Nd) {
  int e = blockIdx.x * 256 + threadIdx.x;
  if (e < Kd * Nd) {
    int k = e / Nd, n = e - k * Nd;
    float v = W[e] * 2048.0f;
    f16 h0 = (f16)v;
    f16 h1 = (f16)(v - (float)h0);
    W0[n * Kd + k] = h0;
    W1[n * Kd + k] = h1;
  }
}

__global__ void cbt_k(const float* __restrict__ cb, float* __restrict__ cbT) {
  int e = blockIdx.x * 256 + threadIdx.x;   // 3*256*64 total
  if (e < 3 * 256 * 64) {
    int l = e >> 14, rem = e & 16383;
    int c = rem >> 6, d = rem & 63;
    cbT[l * 16384 + d * 256 + c] = cb[e];   // [l][d][c]
  }
}

__global__ void nhn_k(const float* __restrict__ cb, float* __restrict__ nhn) {
  int l = blockIdx.x, c = threadIdx.x;      // grid 3 x 256
  const float* p = cb + l * 16384 + c * 64;
  double s = 0.0;
  for (int d = 0; d < 64; ++d) { double v = (double)p[d]; s += v * v; }
  nhn[l * 256 + c] = (float)(-0.5 * s);
}

// ---------------------------------------------------------------------------
// fp32 GEMM, 128x128 tile, BK=32, 8x8 per thread.
// EPI: 0 = SiLU->f32, 1 = +bias->f32, 2 = +bias, LN(128), ReLU -> f32 (needs gridDim.x==1,N==128)
// ---------------------------------------------------------------------------
template <int EPI>
__global__ __launch_bounds__(256, 2) void sgemm128(
    const float* __restrict__ A, const float* __restrict__ W,
    const float* __restrict__ bias, const float* __restrict__ lng,
    const float* __restrict__ lnb, float* __restrict__ C, int N, int Kd) {
  __shared__ float As[32][132];   // [k][m], padded
  __shared__ float Bs[32][128];   // [k][n]
  const int tid = threadIdx.x;
  const int w = tid >> 6, l = tid & 63;
  int tx, ty;
  if (EPI == 2) { tx = tid & 15; ty = tid >> 4; }
  else { tx = ((w & 1) << 3) | (l & 7); ty = ((w >> 1) << 3) | (l >> 3); }
  int bm, bn;
  xcd_swizzle(bm, bn);

  float acc[8][8];
#pragma unroll
  for (int i = 0; i < 8; ++i)
#pragma unroll
    for (int j = 0; j < 8; ++j) acc[i][j] = 0.0f;

  for (int k0 = 0; k0 < Kd; k0 += 32) {
    __syncthreads();
#pragma unroll
    for (int jj = 0; jj < 4; ++jj) {
      int p = tid + 256 * jj;
      int arow = p >> 3, aks = (p & 7) << 2;
      float4 v = *(const float4*)(A + (size_t)(bm + arow) * Kd + k0 + aks);
      As[aks][arow] = v.x; As[aks + 1][arow] = v.y;
      As[aks + 2][arow] = v.z; As[aks + 3][arow] = v.w;
      int bk = p >> 5, bns = (p & 31) << 2;
      float4 u = *(const float4*)(W + (size_t)(k0 + bk) * N + bn + bns);
      *(float4*)(&Bs[bk][bns]) = u;
    }
    __syncthreads();
    float cacc[8][8];
#pragma unroll
    for (int i = 0; i < 8; ++i)
#pragma unroll
      for (int j = 0; j < 8; ++j) cacc[i][j] = 0.0f;
#pragma unroll 4
    for (int kk = 0; kk < 32; ++kk) {
      float a[8], b[8];
#pragma unroll
      for (int i = 0; i < 8; ++i) a[i] = As[kk][ty * 8 + i];
#pragma unroll
      for (int j = 0; j < 8; ++j) b[j] = Bs[kk][tx * 8 + j];
#pragma unroll
      for (int i = 0; i < 8; ++i)
#pragma unroll
        for (int j = 0; j < 8; ++j) cacc[i][j] = fmaf(a[i], b[j], cacc[i][j]);
    }
#pragma unroll
    for (int i = 0; i < 8; ++i)
#pragma unroll
      for (int j = 0; j < 8; ++j) acc[i][j] += cacc[i][j];
  }

  const int colb = bn + tx * 8;
  if (EPI == 0) {
#pragma unroll
    for (int i = 0; i < 8; ++i) {
      int row = bm + ty * 8 + i;
      float o[8];
#pragma unroll
      for (int j = 0; j < 8; ++j) { float v = acc[i][j]; o[j] = v / (1.0f + expf(-v)); }
      *(float4*)(C + (size_t)row * N + colb) = make_float4(o[0], o[1], o[2], o[3]);
      *(float4*)(C + (size_t)row * N + colb + 4) = make_float4(o[4], o[5], o[6], o[7]);
    }
  } else if (EPI == 1) {
    float bb[8];
#pragma unroll
    for (int j = 0; j < 8; ++j) bb[j] = bias[colb + j];
#pragma unroll
    for (int i = 0; i < 8; ++i) {
      int row = bm + ty * 8 + i;
      float o[8];
#pragma unroll
      for (int j = 0; j < 8; ++j) o[j] = acc[i][j] + bb[j];
      *(float4*)(C + (size_t)row * N + colb) = make_float4(o[0], o[1], o[2], o[3]);
      *(float4*)(C + (size_t)row * N + colb + 4) = make_float4(o[4], o[5], o[6], o[7]);
    }
  } else {
    float bb[8], lg[8], lb[8];
#pragma unroll
    for (int j = 0; j < 8; ++j) { bb[j] = bias[colb + j]; lg[j] = lng[colb + j]; lb[j] = lnb[colb + j]; }
#pragma unroll
    for (int i = 0; i < 8; ++i) {
      int row = bm + ty * 8 + i;
      float v[8]; float s = 0.0f;
#pragma unroll
      for (int j = 0; j < 8; ++j) { v[j] = acc[i][j] + bb[j]; s += v[j]; }
      s += __shfl_xor(s, 1); s += __shfl_xor(s, 2); s += __shfl_xor(s, 4); s += __shfl_xor(s, 8);
      float mean = s * (1.0f / 128.0f);
      float ss = 0.0f;
#pragma unroll
      for (int j = 0; j < 8; ++j) { float t = v[j] - mean; ss += t * t; }
      ss += __shfl_xor(ss, 1); ss += __shfl_xor(ss, 2); ss += __shfl_xor(ss, 4); ss += __shfl_xor(ss, 8);
      float rs = 1.0f / sqrtf(ss * (1.0f / 128.0f) + 1e-5f);
      float o[8];
#pragma unroll
      for (int j = 0; j < 8; ++j) o[j] = fmaxf((v[j] - mean) * rs * lg[j] + lb[j], 0.0f);
      *(float4*)(C + (size_t)row * N + colb) = make_float4(o[0], o[1], o[2], o[3]);
      *(float4*)(C + (size_t)row * N + colb + 4) = make_float4(o[4], o[5], o[6], o[7]);
    }
  }
}

// ---------------------------------------------------------------------------
// fp32 GEMM, 128x64 tile (N fixed 64), BK=32, 8x4 per thread.
// EPI: 0 = l2norm row -> C, 1 = +bias -> C, 2 = gate (sigmoid->C, gate*aux->C2)
// ---------------------------------------------------------------------------
template <int EPI>
__global__ __launch_bounds__(256, 2) void sgemm64(
    const float* __restrict__ A, const float* __restrict__ W,
    const float* __restrict__ bias, const float* __restrict__ aux,
    float* __restrict__ C, float* __restrict__ C2, int Kd) {
  __shared__ float As[32][132];
  __shared__ float Bs[32][64];
  const int tid = threadIdx.x;
  const int tx = tid & 15, ty = tid >> 4;
  const int bm = blockIdx.x << 7;

  float acc[8][4];
#pragma unroll
  for (int i = 0; i < 8; ++i)
#pragma unroll
    for (int j = 0; j < 4; ++j) acc[i][j] = 0.0f;

  for (int k0 = 0; k0 < Kd; k0 += 32) {
    __syncthreads();
#pragma unroll
    for (int jj = 0; jj < 4; ++jj) {
      int p = tid + 256 * jj;
      int arow = p >> 3, aks = (p & 7) << 2;
      float4 v = *(const float4*)(A + (size_t)(bm + arow) * Kd + k0 + aks);
      As[aks][arow] = v.x; As[aks + 1][arow] = v.y;
      As[aks + 2][arow] = v.z; As[aks + 3][arow] = v.w;
    }
#pragma unroll
    for (int jj = 0; jj < 2; ++jj) {
      int p = tid + 256 * jj;
      int bk = p >> 4, bns = (p & 15) << 2;
      float4 u = *(const float4*)(W + (size_t)(k0 + bk) * 64 + bns);
      *(float4*)(&Bs[bk][bns]) = u;
    }
    __syncthreads();
    float cacc[8][4];
#pragma unroll
    for (int i = 0; i < 8; ++i)
#pragma unroll
      for (int j = 0; j < 4; ++j) cacc[i][j] = 0.0f;
#pragma unroll 4
    for (int kk = 0; kk < 32; ++kk) {
      float a[8], b[4];
#pragma unroll
      for (int i = 0; i < 8; ++i) a[i] = As[kk][ty * 8 + i];
#pragma unroll
      for (int j = 0; j < 4; ++j) b[j] = Bs[kk][tx * 4 + j];
#pragma unroll
      for (int i = 0; i < 8; ++i)
#pragma unroll
        for (int j = 0; j < 4; ++j) cacc[i][j] = fmaf(a[i], b[j], cacc[i][j]);
    }
#pragma unroll
    for (int i = 0; i < 8; ++i)
#pragma unroll
      for (int j = 0; j < 4; ++j) acc[i][j] += cacc[i][j];
  }

  const int colb = tx * 4;
  if (EPI == 0) {           // l2norm(z) -> rn
#pragma unroll
    for (int i = 0; i < 8; ++i) {
      int row = bm + ty * 8 + i;
      float ss = 0.0f;
#pragma unroll
      for (int j = 0; j < 4; ++j) ss += acc[i][j] * acc[i][j];
      ss += __shfl_xor(ss, 1); ss += __shfl_xor(ss, 2); ss += __shfl_xor(ss, 4); ss += __shfl_xor(ss, 8);
      float nrm = fmaxf(sqrtf(ss), 1e-12f);
      *(float4*)(C + (size_t)row * 64 + colb) =
          make_float4(acc[i][0] / nrm, acc[i][1] / nrm, acc[i][2] / nrm, acc[i][3] / nrm);
    }
  } else if (EPI == 1) {
    float bb[4];
#pragma unroll
    for (int j = 0; j < 4; ++j) bb[j] = bias[colb + j];
#pragma unroll
    for (int i = 0; i < 8; ++i) {
      int row = bm + ty * 8 + i;
      *(float4*)(C + (size_t)row * 64 + colb) =
          make_float4(acc[i][0] + bb[0], acc[i][1] + bb[1], acc[i][2] + bb[2], acc[i][3] + bb[3]);
    }
  } else {                  // gate: sigmoid -> C (gate_values), gate*collab -> C2 (denoised)
    float bb[4];
#pragma unroll
    for (int j = 0; j < 4; ++j) bb[j] = bias[colb + j];
#pragma unroll
    for (int i = 0; i < 8; ++i) {
      int row = bm + ty * 8 + i;
      float4 av = *(const float4*)(aux + (size_t)row * 64 + colb);
      float g[4];
#pragma unroll
      for (int j = 0; j < 4; ++j) g[j] = 1.0f / (1.0f + expf(-(acc[i][j] + bb[j])));
      *(float4*)(C + (size_t)row * 64 + colb) = make_float4(g[0], g[1], g[2], g[3]);
      *(float4*)(C2 + (size_t)row * 64 + colb) =
          make_float4(g[0] * av.x, g[1] * av.y, g[2] * av.z, g[3] * av.w);
    }
  }
}

// ---------------------------------------------------------------------------
// fusion layernorm over 832 = concat(sem 768, denoised 64); wave per row
// ---------------------------------------------------------------------------
__global__ __launch_bounds__(256) void fuse_ln(
    const float* __restrict__ sem, const float* __restrict__ den,
    const float* __restrict__ fg, const float* __restrict__ fb,
    float* __restrict__ fused) {
  const int w = threadIdx.x >> 6, l = threadIdx.x & 63;
  float fgv[13], fbv[13];
#pragma unroll
  for (int q = 0; q < 12; ++q) { fgv[q] = fg[q * 64 + l]; fbv[q] = fb[q * 64 + l]; }
  fgv[12] = fg[768 + l]; fbv[12] = fb[768 + l];
  for (int it = 0; it < 4; ++it) {
    int r = (blockIdx.x * 4 + w) * 4 + it;
    float sv[12];
#pragma unroll
    for (int q = 0; q < 12; ++q) sv[q] = sem[(size_t)r * 768 + q * 64 + l];
    float dv = den[(size_t)r * 64 + l];
    float s = dv;
#pragma unroll
    for (int q = 0; q < 12; ++q) s += sv[q];
#pragma unroll
    for (int m = 1; m < 64; m <<= 1) s += __shfl_xor(s, m, 64);
    float mean = s * (1.0f / 832.0f);
    float t0 = dv - mean;
    float ss = t0 * t0;
#pragma unroll
    for (int q = 0; q < 12; ++q) { float t = sv[q] - mean; ss += t * t; }
#pragma unroll
    for (int m = 1; m < 64; m <<= 1) ss += __shfl_xor(ss, m, 64);
    float sc = 1.0f / sqrtf(ss * (1.0f / 832.0f) + 1e-5f);
#pragma unroll
    for (int q = 0; q < 12; ++q)
      fused[(size_t)r * 832 + q * 64 + l] = (sv[q] - mean) * sc * fgv[q] + fbv[q];
    fused[(size_t)r * 832 + 768 + l] = t0 * sc * fgv[12] + fbv[12];
  }
}

// ---------------------------------------------------------------------------
// RQ argmax + update; wave per row, 16 rows/wave
// ---------------------------------------------------------------------------
template <int LAYER>
__global__ __launch_bounds__(256) void argupd(
    const float* __restrict__ scores, const float* __restrict__ cbl,
    float* __restrict__ rn, float* __restrict__ zq, float* __restrict__ codes,
    float* __restrict__ loss, bf16* __restrict__ zqb) {
  const int w = threadIdx.x >> 6, l = threadIdx.x & 63;
  const int base = (blockIdx.x * 4 + w) * 16;
  float lacc = 0.0f;
  for (int it = 0; it < 16; ++it) {
    int r = base + it;
    float4 s4 = *(const float4*)(scores + (size_t)r * 256 + l * 4);
    float bs = s4.x; int bi = l * 4;
    if (s4.y > bs) { bs = s4.y; bi = l * 4 + 1; }
    if (s4.z > bs) { bs = s4.z; bi = l * 4 + 2; }
    if (s4.w > bs) { bs = s4.w; bi = l * 4 + 3; }
#pragma unroll
    for (int m = 1; m < 64; m <<= 1) {
      float os = __shfl_xor(bs, m, 64);
      int oi = __shfl_xor(bi, m, 64);
      if (os > bs || (os == bs && oi < bi)) { bs = os; bi = oi; }
    }
    float e = cbl[bi * 64 + l];
    float rl = rn[(size_t)r * 64 + l];
    float emr = e - rl;
    float zql = rl + emr;          // straight-through forward value, ref rounding order
    lacc += emr * emr;
    if (l == 0) codes[r * 3 + LAYER] = (float)bi;
    if (LAYER == 0) {
      zq[(size_t)r * 64 + l] = zql;
    } else if (LAYER == 1) {
      zq[(size_t)r * 64 + l] += zql;
    } else {
      float tot = zq[(size_t)r * 64 + l] + zql;
      zq[(size_t)r * 64 + l] = tot;
      zqb[(size_t)r * 64 + l] = (bf16)tot;
    }
    if (LAYER < 2) {
      float rnew = rl - zql;
      float ss = rnew * rnew;
#pragma unroll
      for (int m = 1; m < 64; m <<= 1) ss += __shfl_xor(ss, m, 64);
      float nrm = fmaxf(sqrtf(ss), 1e-12f);
      rn[(size_t)r * 64 + l] = rnew / nrm;
    }
  }
#pragma unroll
  for (int m = 1; m < 64; m <<= 1) lacc += __shfl_xor(lacc, m, 64);
  if (l == 0) {
    float v = lacc * (1.0f / 4194304.0f);   // 1/(65536*64), exact pow2
    atomicAdd(loss, v);
    atomicAdd(loss + 1, v);
  }
}

// ---------------------------------------------------------------------------
// async global->LDS helper
// ---------------------------------------------------------------------------
typedef __attribute__((address_space(3))) void lds_void_t;
typedef __attribute__((address_space(1))) const void gbl_void_t;
__device__ __forceinline__ void gl_lds16(const void* g, void* l) {
  __builtin_amdgcn_global_load_lds((gbl_void_t*)g, (lds_void_t*)l, 16, 0, 0);
}

// ---------------------------------------------------------------------------
// fp32-accurate GEMM via 2-way fp16 split + 3 MFMA products (m97 structure).
// A fp32 (split on the fly, x256); W pre-split fp16 planes [N][K] (x2048).
// Epilogue: SiLU(acc * 2^-19) -> fp32.
// ---------------------------------------------------------------------------
__global__ __launch_bounds__(256, 3) void hgemm3(
    const float* __restrict__ A, const f16* __restrict__ W0,
    const f16* __restrict__ W1, float* __restrict__ C, int N, int Kd) {
  __shared__ __align__(16) f16 As0[128 * 32];
  __shared__ __align__(16) f16 As1[128 * 32];
  __shared__ __align__(16) f16 Bs0[128 * 32];
  __shared__ __align__(16) f16 Bs1[128 * 32];
  const int tid = threadIdx.x;
  const int w = tid >> 6, l = tid & 63;
  int bm, bn;
  xcd_swizzle(bm, bn);
  const int wm = (w >> 1) << 6, wn = (w & 1) << 6;

  v4f acc[4][4];
  v4f z4 = {0.0f, 0.0f, 0.0f, 0.0f};
#pragma unroll
  for (int i = 0; i < 4; ++i)
#pragma unroll
    for (int j = 0; j < 4; ++j) acc[i][j] = z4;

  const int srow = (w << 5) + (l >> 2);
  const int skc = (l & 3) << 3;                 // halves
  const f16* gb0 = W0 + (size_t)(bn + srow) * Kd + skc;
  const f16* gb1 = W1 + (size_t)(bn + srow) * Kd + skc;
  char* lb0 = (char*)Bs0 + (w << 11);
  char* lb1 = (char*)Bs1 + (w << 11);

  for (int k0 = 0; k0 < Kd; k0 += 32) {
    __syncthreads();
    gl_lds16(gb0 + k0, lb0);
    gl_lds16(gb0 + (size_t)16 * Kd + k0, lb0 + 1024);
    gl_lds16(gb1 + k0, lb1);
    gl_lds16(gb1 + (size_t)16 * Kd + k0, lb1 + 1024);
#pragma unroll
    for (int jj = 0; jj < 4; ++jj) {
      int idx = tid + 256 * jj;
      int row = idx >> 3, kq = (idx & 7) << 2;
      float4 v = *(const float4*)(A + (size_t)(bm + row) * Kd + k0 + kq);
      v4h h0, h1;
      float x;
      x = v.x * 256.0f; h0.x = (f16)x; h1.x = (f16)(x - (float)h0.x);
      x = v.y * 256.0f; h0.y = (f16)x; h1.y = (f16)(x - (float)h0.y);
      x = v.z * 256.0f; h0.z = (f16)x; h1.z = (f16)(x - (float)h0.z);
      x = v.w * 256.0f; h0.w = (f16)x; h1.w = (f16)(x - (float)h0.w);
      *(v4h*)(&As0[row * 32 + kq]) = h0;
      *(v4h*)(&As1[row * 32 + kq]) = h1;
    }
    __syncthreads();
    v8h a0f[4], a1f[4], b0f[4], b1f[4];
#pragma unroll
    for (int f = 0; f < 4; ++f) {
      int ro = (wm + f * 16 + (l & 15)) * 32 + ((l >> 4) << 3);
      int co = (wn + f * 16 + (l & 15)) * 32 + ((l >> 4) << 3);
      a0f[f] = *(const v8h*)(As0 + ro);
      a1f[f] = *(const v8h*)(As1 + ro);
      b0f[f] = *(const v8h*)(Bs0 + co);
      b1f[f] = *(const v8h*)(Bs1 + co);
    }
#pragma unroll
    for (int mf = 0; mf < 4; ++mf)
#pragma unroll
      for (int nf = 0; nf < 4; ++nf) {
        acc[mf][nf] = __builtin_amdgcn_mfma_f32_16x16x32_f16(a0f[mf], b1f[nf], acc[mf][nf], 0, 0, 0);
        acc[mf][nf] = __builtin_amdgcn_mfma_f32_16x16x32_f16(a1f[mf], b0f[nf], acc[mf][nf], 0, 0, 0);
        acc[mf][nf] = __builtin_amdgcn_mfma_f32_16x16x32_f16(a0f[mf], b0f[nf], acc[mf][nf], 0, 0, 0);
      }
  }

  const float sc = 1.0f / (256.0f * 2048.0f);   // 2^-19 exact
  const int cbase = bn + wn + (l & 15);
#pragma unroll
  for (int mf = 0; mf < 4; ++mf) {
#pragma unroll
    for (int i = 0; i < 4; ++i) {
      int row = bm + wm + mf * 16 + ((l >> 4) << 2) + i;
#pragma unroll
      for (int nf = 0; nf < 4; ++nf) {
        int col = cbase + nf * 16;
        float v = acc[mf][nf][i] * sc;
        v = v / (1.0f + expf(-v));              // SiLU, precision path
        C[(size_t)row * N + col] = v;
      }
    }
  }
}

// ---------------------------------------------------------------------------
// bf16 MFMA GEMM (gemm_bt, m97 structure): 128x128 tile, BK=32, global_load_lds
// EPI: 0 = SiLU->bf16, 1 = +bias->bf16, 2 = +bias->f32
// ---------------------------------------------------------------------------
template <int EPI>
__global__ __launch_bounds__(256, 3) void bgemm(
    const bf16* __restrict__ A, const bf16* __restrict__ Wt,
    const float* __restrict__ bias, void* __restrict__ Cv, int N, int Kd) {
  __shared__ __align__(16) bf16 As[128 * 32];
  __shared__ __align__(16) bf16 Bs[128 * 32];
  const int tid = threadIdx.x;
  const int w = tid >> 6, l = tid & 63;
  int bm, bn;
  xcd_swizzle(bm, bn);
  const int wm = (w >> 1) << 6, wn = (w & 1) << 6;

  v4f acc[4][4];
  v4f z4 = {0.0f, 0.0f, 0.0f, 0.0f};
#pragma unroll
  for (int i = 0; i < 4; ++i)
#pragma unroll
    for (int j = 0; j < 4; ++j) acc[i][j] = z4;

  const int srow = (w << 5) + (l >> 2);
  const int skc = (l & 3) << 3;
  const bf16* ga0 = A + (size_t)(bm + srow) * Kd + skc;
  const bf16* gb0 = Wt + (size_t)(bn + srow) * Kd + skc;
  char* la0 = (char*)As + (w << 11);
  char* lb0 = (char*)Bs + (w << 11);

  for (int k0 = 0; k0 < Kd; k0 += 32) {
    __syncthreads();
    gl_lds16(ga0 + k0, la0);
    gl_lds16(ga0 + (size_t)16 * Kd + k0, la0 + 1024);
    gl_lds16(gb0 + k0, lb0);
    gl_lds16(gb0 + (size_t)16 * Kd + k0, lb0 + 1024);
    __syncthreads();
    v8bf af[4], bfr[4];
#pragma unroll
    for (int f = 0; f < 4; ++f) {
      af[f] = *(const v8bf*)(As + (wm + f * 16 + (l & 15)) * 32 + ((l >> 4) << 3));
      bfr[f] = *(const v8bf*)(Bs + (wn + f * 16 + (l & 15)) * 32 + ((l >> 4) << 3));
    }
#pragma unroll
    for (int mf = 0; mf < 4; ++mf)
#pragma unroll
      for (int nf = 0; nf < 4; ++nf)
        acc[mf][nf] = __builtin_amdgcn_mfma_f32_16x16x32_bf16(af[mf], bfr[nf], acc[mf][nf], 0, 0, 0);
  }

  const int cbase = bn + wn + (l & 15);
  float bb[4];
  if (EPI != 0) {
#pragma unroll
    for (int nf = 0; nf < 4; ++nf) bb[nf] = bias[cbase + nf * 16];
  }
#pragma unroll
  for (int mf = 0; mf < 4; ++mf) {
#pragma unroll
    for (int i = 0; i < 4; ++i) {
      int row = bm + wm + mf * 16 + ((l >> 4) << 2) + i;
#pragma unroll
      for (int nf = 0; nf < 4; ++nf) {
        int col = cbase + nf * 16;
        float v = acc[mf][nf][i];
        if (EPI == 0) {
          v = v / (1.0f + __expf(-v));
          ((bf16*)Cv)[(size_t)row * N + col] = (bf16)v;
        } else if (EPI == 1) {
          v += bb[nf];
          ((bf16*)Cv)[(size_t)row * N + col] = (bf16)v;
        } else {
          v += bb[nf];
          ((float*)Cv)[(size_t)row * N + col] = v;
        }
      }
    }
  }
}

// ---------------------------------------------------------------------------
// row layernorm + relu, in place; block per row
// ---------------------------------------------------------------------------
template <int VPT, typename T>
__global__ __launch_bounds__(256) void ln_relu(T* __restrict__ x,
    const float* __restrict__ g, const float* __restrict__ b) {
  const int N = VPT * 256;
  const size_t base = (size_t)blockIdx.x * N;
  const int tid = threadIdx.x, w = tid >> 6, l = tid & 63;
  float v[VPT];
#pragma unroll
  for (int q = 0; q < VPT; ++q) v[q] = (float)x[base + q * 256 + tid];
  float s = 0.0f;
#pragma unroll
  for (int q = 0; q < VPT; ++q) s += v[q];
#pragma unroll
  for (int m = 1; m < 64; m <<= 1) s += __shfl_xor(s, m, 64);
  __shared__ float red[8];
  if (l == 0) red[w] = s;
  __syncthreads();
  float mean = (red[0] + red[1] + red[2] + red[3]) * (1.0f / N);
  float ss = 0.0f;
#pragma unroll
  for (int q = 0; q < VPT; ++q) { float t = v[q] - mean; ss += t * t; }
#pragma unroll
  for (int m = 1; m < 64; m <<= 1) ss += __shfl_xor(ss, m, 64);
  if (l == 0) red[4 + w] = ss;
  __syncthreads();
  float var = (red[4] + red[5] + red[6] + red[7]) * (1.0f / N);
  float rs = 1.0f / sqrtf(var + 1e-5f);
#pragma unroll
  for (int q = 0; q < VPT; ++q) {
    int j = q * 256 + tid;
    float y = (v[q] - mean) * rs * g[j] + b[j];
    x[base + j] = (T)fmaxf(y, 0.0f);
  }
}

// ---------------------------------------------------------------------------
// launch
// ---------------------------------------------------------------------------
extern "C" void kernel_launch(void* const* d_in, const int* in_sizes, int n_in,
                              void* d_out, int out_size, void* d_ws, size_t ws_size,
                              hipStream_t stream) {
  (void)in_sizes; (void)n_in; (void)out_size; (void)ws_size;
  const float* semI  = (const float*)d_in[0];
  const float* colI  = (const float*)d_in[1];
  const float* gw1   = (const float*)d_in[2];
  const float* gb1   = (const float*)d_in[3];
  const float* glng  = (const float*)d_in[4];
  const float* glnb  = (const float*)d_in[5];
  const float* gw2   = (const float*)d_in[6];
  const float* gb2   = (const float*)d_in[7];
  const float* fg    = (const float*)d_in[8];
  const float* fb    = (const float*)d_in[9];
  const float* ew1   = (const float*)d_in[10];
  const float* ew2   = (const float*)d_in[11];
  const float* ew3   = (const float*)d_in[12];
  const float* ew4   = (const float*)d_in[13];
  const float* dw1   = (const float*)d_in[14];
  const float* dw2   = (const float*)d_in[15];
  const float* dw3   = (const float*)d_in[16];
  const float* sw1   = (const float*)d_in[17];
  const float* sb1   = (const float*)d_in[18];
  const float* slng  = (const float*)d_in[19];
  const float* slnb  = (const float*)d_in[20];
  const float* sw2   = (const float*)d_in[21];
  const float* sb2   = (const float*)d_in[22];
  const float* cw1   = (const float*)d_in[23];
  const float* cb1   = (const float*)d_in[24];
  const float* clng  = (const float*)d_in[25];
  const float* clnb  = (const float*)d_in[26];
  const float* cw2   = (const float*)d_in[27];
  const float* cb2   = (const float*)d_in[28];
  const float* cbk   = (const float*)d_in[29];

  float* out = (float*)d_out;
  char* ws = (char*)d_ws;

  // output offsets (floats)
  const size_t OUT_SEM = 0, OUT_COL = 50331648, OUT_ZQ = 54525952,
               OUT_CODES = 58720256, OUT_CB = 58916864, OUT_GATE = 58916866;

  // ws layout (bytes)
  bf16* dec1t = (bf16*)(ws + 0);
  bf16* dec2t = (bf16*)(ws + 16384);
  bf16* dec3t = (bf16*)(ws + 81920);
  bf16* sem1t = (bf16*)(ws + 344064);
  bf16* sem2t = (bf16*)(ws + 1916928);
  bf16* col1t = (bf16*)(ws + 4276224);
  float* cbT  = (float*)(ws + 4538368);
  float* nhn  = (float*)(ws + 4734976);
  f16* e1w0   = (f16*)(ws + 4739072);
  f16* e1w1   = (f16*)(ws + 5591040);
  f16* e2w0   = (f16*)(ws + 6443008);
  f16* e2w1   = (f16*)(ws + 6705152);
  f16* e3w0   = (f16*)(ws + 6967296);
  f16* e3w1   = (f16*)(ws + 7032832);
  const size_t WS_A = 8388608, WS_B = 226492416;
  float* fused  = (float*)(ws + WS_A);
  float* scores = (float*)(ws + WS_A);            // reuses fused after E1
  bf16*  semh   = (bf16*)(ws + WS_A);             // reuses scores after RQ
  float* den = (float*)(ws + WS_B);               // pre-E1 temp
  float* hn  = (float*)(ws + WS_B + 16777216);    // pre-E1 temp
  float* h1  = (float*)(ws + WS_B);
  float* h2  = (float*)(ws + 360710144);
  float* h3  = (float*)(ws + 427819008);
  float* rn  = (float*)(ws + 461373440);
  bf16* zqb  = (bf16*)(ws + WS_B);
  bf16* d1b  = (bf16*)(ws + WS_B + 8388608);
  bf16* d2b  = (bf16*)(ws + WS_B + 25165824);
  bf16* sb   = (bf16*)(ws + WS_B + 58720256);
  float* colh = (float*)(ws + WS_B + 125829120);

  // zero the two loss scalars (d_out is poisoned each launch)
  hipMemsetAsync(out + OUT_CB, 0, 2 * sizeof(float), stream);

  // weight prep
  wconv_t<<<(64 * 128 + 255) / 256, 256, 0, stream>>>(dw1, dec1t, 64, 128);
  wconv_t<<<(128 * 256 + 255) / 256, 256, 0, stream>>>(dw2, dec2t, 128, 256);
  wconv_t<<<(256 * 512 + 255) / 256, 256, 0, stream>>>(dw3, dec3t, 256, 512);
  wconv_t<<<(512 * 1536 + 255) / 256, 256, 0, stream>>>(sw1, sem1t, 512, 1536);
  wconv_t<<<(1536 * 768 + 255) / 256, 256, 0, stream>>>(sw2, sem2t, 1536, 768);
  wconv_t<<<(512 * 256 + 255) / 256, 256, 0, stream>>>(cw1, col1t, 512, 256);
  wsplit_t<<<(832 * 512 + 255) / 256, 256, 0, stream>>>(ew1, e1w0, e1w1, 832, 512);
  wsplit_t<<<(512 * 256 + 255) / 256, 256, 0, stream>>>(ew2, e2w0, e2w1, 512, 256);
  wsplit_t<<<(256 * 128 + 255) / 256, 256, 0, stream>>>(ew3, e3w0, e3w1, 256, 128);
  cbt_k<<<192, 256, 0, stream>>>(cbk, cbT);
  nhn_k<<<3, 256, 0, stream>>>(cbk, nhn);

  // gate network (fp32)
  sgemm128<2><<<dim3(1, 512), 256, 0, stream>>>(colI, gw1, gb1, glng, glnb, hn, 128, 64);
  sgemm64<2><<<512, 256, 0, stream>>>(hn, gw2, gb2, colI, out + OUT_GATE, den, 128);
  fuse_ln<<<4096, 256, 0, stream>>>(semI, den, fg, fb, fused);

  // encoder (fp32-accurate via fp16 split MFMA)
  hgemm3<<<dim3(4, 512), 256, 0, stream>>>(fused, e1w0, e1w1, h1, 512, 832);
  hgemm3<<<dim3(2, 512), 256, 0, stream>>>(h1, e2w0, e2w1, h2, 256, 512);
  hgemm3<<<dim3(1, 512), 256, 0, stream>>>(h2, e3w0, e3w1, h3, 128, 256);
  sgemm64<0><<<512, 256, 0, stream>>>(h3, ew4, nullptr, nullptr, rn, nullptr, 128);

  // residual quantization (fp32 scores as GEMM + argmax/update)
  sgemm128<1><<<dim3(2, 512), 256, 0, stream>>>(rn, cbT + 0 * 16384, nhn + 0, nullptr, nullptr, scores, 256, 64);
  argupd<0><<<1024, 256, 0, stream>>>(scores, cbk + 0 * 16384, rn, out + OUT_ZQ, out + OUT_CODES, out + OUT_CB, zqb);
  sgemm128<1><<<dim3(2, 512), 256, 0, stream>>>(rn, cbT + 1 * 16384, nhn + 256, nullptr, nullptr, scores, 256, 64);
  argupd<1><<<1024, 256, 0, stream>>>(scores, cbk + 1 * 16384, rn, out + OUT_ZQ, out + OUT_CODES, out + OUT_CB, zqb);
  sgemm128<1><<<dim3(2, 512), 256, 0, stream>>>(rn, cbT + 2 * 16384, nhn + 512, nullptr, nullptr, scores, 256, 64);
  argupd<2><<<1024, 256, 0, stream>>>(scores, cbk + 2 * 16384, rn, out + OUT_ZQ, out + OUT_CODES, out + OUT_CB, zqb);

  // decoder + heads (bf16 MFMA)
  bgemm<0><<<dim3(1, 512), 256, 0, stream>>>(zqb, dec1t, nullptr, d1b, 128, 64);
  bgemm<0><<<dim3(2, 512), 256, 0, stream>>>(d1b, dec2t, nullptr, d2b, 256, 128);
  bgemm<0><<<dim3(4, 512), 256, 0, stream>>>(d2b, dec3t, nullptr, sb, 512, 256);
  bgemm<1><<<dim3(12, 512), 256, 0, stream>>>(sb, sem1t, sb1, semh, 1536, 512);
  ln_relu<6, bf16><<<65536, 256, 0, stream>>>(semh, slng, slnb);
  bgemm<2><<<dim3(6, 512), 256, 0, stream>>>(semh, sem2t, sb2, out + OUT_SEM, 768, 1536);
  bgemm<2><<<dim3(2, 512), 256, 0, stream>>>(sb, col1t, cb1, colh, 256, 512);
  ln_relu<1, float><<<65536, 256, 0, stream>>>(colh, clng, clnb);
  sgemm64<1><<<512, 256, 0, stream>>>(colh, cw2, cb2, nullptr, out + OUT_COL, nullptr, 256);
}